// Round 1
// baseline (481.461 us; speedup 1.0000x reference)
//
#include <hip/hip_runtime.h>
#include <cstdint>
#include <cstddef>

#define IN_DIM  768
#define NNODES  10000
#define MPAD    10240        // 40 * 256  (also 80 * 128 for the proj GEMM)
#define NEDGES  80000
#define E_TOT   90000        // edges + self loops
#define HEADS   8
#define HID     256
#define HC      2048         // HEADS*HID
#define NEG_SLOPE 0.2f

// prep_kernel block ranges (256 threads each)
#define CVT_BLK  ((MPAD * IN_DIM / 4) / 256)          // 7680
#define CNT_BLK  ((E_TOT + 255) / 256)                // 352
#define T1_BLK   ((HC / 32) * (IN_DIM / 32))          // 1536
#define T2_BLK   ((HC / 32) * (HC / 32))              // 4096
#define TP_BLK   ((HID / 32) * (HID / 32))            // 64
#define PREP_BLK (CVT_BLK + CNT_BLK + T1_BLK + T2_BLK + TP_BLK)

typedef _Float16 __attribute__((ext_vector_type(8))) f16x8;
typedef float    __attribute__((ext_vector_type(4))) f32x4;

// ---------------------------------------------------------------------------
// edge helpers: edge ids [0,NEDGES) are real edges, [NEDGES,E_TOT) self loops
// ---------------------------------------------------------------------------
__device__ __forceinline__ int edge_src(const int* __restrict__ ei, int e) {
    return (e < NEDGES) ? ei[e] : (e - NEDGES);
}
__device__ __forceinline__ int edge_dst(const int* __restrict__ ei, int e) {
    return (e < NEDGES) ? ei[NEDGES + e] : (e - NEDGES);
}

// ---------------------------------------------------------------------------
// fused preprocessing (R9-proven): cvt + edge count + 3 weight transposes
// ---------------------------------------------------------------------------
__device__ __forceinline__ void tcvt_body(
    const float* __restrict__ W, _Float16* __restrict__ T,
    int K, int N, int bx, int by, int t)
{
    __shared__ float tile[32][33];
    int tx = t & 31, ty = t >> 5;   // 32 x 8
#pragma unroll
    for (int q = 0; q < 4; q++)
        tile[ty + q * 8][tx] = W[(size_t)(by * 32 + ty + q * 8) * N + bx * 32 + tx];
    __syncthreads();
#pragma unroll
    for (int q = 0; q < 4; q++) {
        float v = tile[tx][ty + q * 8];
        T[(size_t)(bx * 32 + ty + q * 8) * K + by * 32 + tx] = (_Float16)v;
    }
}

__global__ __launch_bounds__(256) void prep_kernel(
    const float* __restrict__ x, _Float16* __restrict__ xh,
    const int* __restrict__ ei, int* __restrict__ cnt,
    const float* __restrict__ W1, _Float16* __restrict__ W1t,
    const float* __restrict__ W2, _Float16* __restrict__ W2t,
    const float* __restrict__ Wp, _Float16* __restrict__ Wpt)
{
    int b = blockIdx.x;
    int t = threadIdx.x;
    if (b < CVT_BLK) {
        int i = b * 256 + t;
        size_t e = (size_t)i * 4;
        int r = (int)(e / IN_DIM);
        float4 v = (r < NNODES) ? *(const float4*)(x + e)
                                : make_float4(0.f, 0.f, 0.f, 0.f);
        _Float16 h4[4] = {(_Float16)v.x, (_Float16)v.y, (_Float16)v.z, (_Float16)v.w};
        *(ushort4*)(xh + e) = *(ushort4*)h4;
    } else if (b < CVT_BLK + CNT_BLK) {
        int e = (b - CVT_BLK) * 256 + t;
        if (e < E_TOT) atomicAdd(&cnt[edge_dst(ei, e)], 1);
    } else if (b < CVT_BLK + CNT_BLK + T1_BLK) {
        int idx = b - (CVT_BLK + CNT_BLK);
        tcvt_body(W1, W1t, IN_DIM, HC, idx % (HC / 32), idx / (HC / 32), t);
    } else if (b < CVT_BLK + CNT_BLK + T1_BLK + T2_BLK) {
        int idx = b - (CVT_BLK + CNT_BLK + T1_BLK);
        tcvt_body(W2, W2t, HC, HC, idx % (HC / 32), idx / (HC / 32), t);
    } else {
        int idx = b - (CVT_BLK + CNT_BLK + T1_BLK + T2_BLK);
        tcvt_body(Wp, Wpt, HID, HID, idx % (HID / 32), idx / (HID / 32), t);
    }
}

// ---------------------------------------------------------------------------
// CSR: scan + scatter (count fused into prep_kernel)
// ---------------------------------------------------------------------------
__global__ void scan_kernel(const int* __restrict__ cnt, int* __restrict__ indptr) {
    __shared__ int sums[1024];
    const int CH = 10;
    int t = threadIdx.x;
    int base = t * CH;
    int s = 0;
#pragma unroll
    for (int i = 0; i < CH; i++) { int idx = base + i; if (idx < NNODES) s += cnt[idx]; }
    sums[t] = s;
    __syncthreads();
    for (int off = 1; off < 1024; off <<= 1) {
        int v = (t >= off) ? sums[t - off] : 0;
        __syncthreads();
        sums[t] += v;
        __syncthreads();
    }
    int run = (t == 0) ? 0 : sums[t - 1];
#pragma unroll
    for (int i = 0; i < CH; i++) {
        int idx = base + i;
        if (idx < NNODES) { indptr[idx] = run; run += cnt[idx]; }
    }
    if (t == 0) indptr[NNODES] = E_TOT;
}

__global__ void scatter_kernel(const int* __restrict__ ei, const int* __restrict__ indptr,
                               int* __restrict__ cur, int* __restrict__ sorted) {
    int e = blockIdx.x * 256 + threadIdx.x;
    if (e < E_TOT) {
        int d = edge_dst(ei, e);
        int pos = atomicAdd(&cur[d], 1);
        sorted[indptr[d] + pos] = e;
    }
}

// ---------------------------------------------------------------------------
// 8-phase 256x256 fp16 MFMA GEMM (m201 template, plain HIP):
//   C[M,Nn] = A[Mpad,K] @ B[Nn,K]^T,  fp16 out, guard m < M.
// BM=BN=256, BK=64, 512 thr = 8 waves (2M x 4N). LDS 128 KiB:
//   lds[buf][half][128*64], halves: 0=A rows 0-127, 1=A rows 128-255,
//                                   2=B rows 0-127, 3=B rows 128-255.
// Per K-tile: 4 phases, phase = one 128x128 block-C quadrant over K=64
//   (reads exactly A-half qm + B-half qn; 16 MFMA/wave).
// T2 swizzle: 16B slot s of row r holds global k-slot (s ^ (r&7))  — applied
//   on the global SOURCE address (global_load_lds dest stays linear, rule #21)
//   and on the ds_read address (involution).
// T3/T4: stage order {A0,B0,B1,A1} for tile t+1 during tile t's 4 phases ->
//   every half has stage->first-read distance >= 3 phases; vmcnt(4) before the
//   pre-MFMA barrier each phase guarantees "all stages older than 2 half-tiles
//   landed" chip-wide; never drains to 0 except prologue + final tile.
// T5: setprio(1) around the MFMA cluster.
// Requires K%64==0, K/64>=2, Nn%256==0, gridDim=(Nn/256, Mpad/256), nwg%8==0.
// ---------------------------------------------------------------------------
__global__ __launch_bounds__(512, 2) void gemm8p_kernel(
    const _Float16* __restrict__ A, const _Float16* __restrict__ B,
    _Float16* __restrict__ C, int M, int K, int Nn)
{
    __shared__ __align__(16) _Float16 lds[2][4][128 * 64];   // 128 KiB

    const int t = threadIdx.x;
    const int w = t >> 6, lane = t & 63;
    const int fr = lane & 15, q4 = lane >> 4;
    const int wr = w >> 2, wc = w & 3;        // 2 x 4 wave grid

    // bijective XCD chunk swizzle (nwg % 8 == 0 by construction)
    const int nwgx = gridDim.x;
    int wg = blockIdx.y * nwgx + blockIdx.x;
    const int cpx = (nwgx * gridDim.y) >> 3;
    wg = (wg & 7) * cpx + (wg >> 3);
    const int row0 = (wg / nwgx) * 256;
    const int col0 = (wg % nwgx) * 256;

    // staging: load q in {0,1}: idx = q*512 + t -> row idx>>3, 16B slot idx&7.
    // pre-swizzled global column so linear LDS holds the swizzled layout.
    const int srow0 = t >> 3,         sslot0 = t & 7;
    const int srow1 = (t + 512) >> 3, sslot1 = (t + 512) & 7;
    const int scol0 = (sslot0 ^ (srow0 & 7)) << 3;
    const int scol1 = (sslot1 ^ (srow1 & 7)) << 3;
    const int ldso0 = (w * 64) << 3;          // (q*512 + w*64)*8 halves, q=0
    const int ldso1 = (512 + w * 64) << 3;    // q=1 (wave-uniform dest bases)

    auto stage = [&](int half, int kel, int bb) {
        const _Float16* P;
        int rbase;
        if (half >= 2) { P = B; rbase = col0 + (half - 2) * 128; }
        else           { P = A; rbase = row0 + half * 128; }
        const _Float16* s0 = P + (size_t)(rbase + srow0) * K + kel + scol0;
        const _Float16* s1 = P + (size_t)(rbase + srow1) * K + kel + scol1;
        __builtin_amdgcn_global_load_lds(
            (const __attribute__((address_space(1))) void*)s0,
            (__attribute__((address_space(3))) void*)&lds[bb][half][ldso0], 16, 0, 0);
        __builtin_amdgcn_global_load_lds(
            (const __attribute__((address_space(1))) void*)s1,
            (__attribute__((address_space(3))) void*)&lds[bb][half][ldso1], 16, 0, 0);
    };

    f32x4 acc[2][2][4][2];
#pragma unroll
    for (int qm = 0; qm < 2; qm++)
#pragma unroll
        for (int qn = 0; qn < 2; qn++)
#pragma unroll
            for (int mi = 0; mi < 4; mi++)
#pragma unroll
                for (int ni = 0; ni < 2; ni++)
                    acc[qm][qn][mi][ni] = {0.f, 0.f, 0.f, 0.f};

// one phase: quadrant (QM,QN) of tile in buf BB; optionally stage half SH of
// the next tile (element k-offset KT1) into buf BB^1.  VMN is the literal
// vmcnt bound (4 steady state, 0 on the final tile).
#define PHASE(QM, QN, BB, SH, KT1, DOSTAGE, VMN)                                \
    do {                                                                        \
        f16x8 fa[4][2], fb[2][2];                                               \
        _Pragma("unroll")                                                       \
        for (int mi = 0; mi < 4; mi++) {                                        \
            _Pragma("unroll")                                                   \
            for (int ks = 0; ks < 2; ks++) {                                    \
                int lr = wr * 64 + mi * 16 + fr;                                \
                int sl = ((ks << 2) | q4) ^ (fr & 7);                           \
                fa[mi][ks] = *(const f16x8*)&lds[BB][QM][(lr << 6) + (sl << 3)];\
            }                                                                   \
        }                                                                       \
        _Pragma("unroll")                                                       \
        for (int ni = 0; ni < 2; ni++) {                                        \
            _Pragma("unroll")                                                   \
            for (int ks = 0; ks < 2; ks++) {                                    \
                int lr = wc * 32 + ni * 16 + fr;                                \
                int sl = ((ks << 2) | q4) ^ (fr & 7);                           \
                fb[ni][ks] = *(const f16x8*)&lds[BB][2 + QN][(lr << 6) + (sl << 3)];\
            }                                                                   \
        }                                                                       \
        if (DOSTAGE) stage(SH, KT1, (BB) ^ 1);                                  \
        asm volatile("s_waitcnt vmcnt(" #VMN ")" ::: "memory");                 \
        __builtin_amdgcn_s_barrier();                                           \
        asm volatile("s_waitcnt lgkmcnt(0)" ::: "memory");                      \
        __builtin_amdgcn_sched_barrier(0);                                      \
        __builtin_amdgcn_s_setprio(1);                                          \
        _Pragma("unroll")                                                       \
        for (int ks = 0; ks < 2; ks++) {                                        \
            _Pragma("unroll")                                                   \
            for (int mi = 0; mi < 4; mi++) {                                    \
                _Pragma("unroll")                                               \
                for (int ni = 0; ni < 2; ni++)                                  \
                    acc[QM][QN][mi][ni] = __builtin_amdgcn_mfma_f32_16x16x32_f16(\
                        fa[mi][ks], fb[ni][ks], acc[QM][QN][mi][ni], 0, 0, 0);  \
            }                                                                   \
        }                                                                       \
        __builtin_amdgcn_s_setprio(0);                                          \
        __builtin_amdgcn_sched_barrier(0);                                      \
        __builtin_amdgcn_s_barrier();                                           \
    } while (0)

    // prologue: tile 0 fully staged, one-time drain
    stage(0, 0, 0); stage(2, 0, 0); stage(3, 0, 0); stage(1, 0, 0);
    asm volatile("s_waitcnt vmcnt(0)" ::: "memory");
    __builtin_amdgcn_s_barrier();

    const int nT = K >> 6;
    int t0 = 0;
    for (; t0 < nT - 1; ++t0) {
        int bb = t0 & 1;
        int kt1 = (t0 + 1) << 6;
        PHASE(0, 0, bb, 0, kt1, 1, 4);   // stage A0(t+1)
        PHASE(0, 1, bb, 2, kt1, 1, 4);   // stage B0(t+1)
        PHASE(1, 0, bb, 3, kt1, 1, 4);   // stage B1(t+1)
        PHASE(1, 1, bb, 1, kt1, 1, 4);   // stage A1(t+1)
    }
    {   // final tile: no prefetch, drain once at its first phase
        int bb = t0 & 1;
        PHASE(0, 0, bb, 0, 0, 0, 0);
        PHASE(0, 1, bb, 0, 0, 0, 0);
        PHASE(1, 0, bb, 0, 0, 0, 0);
        PHASE(1, 1, bb, 0, 0, 0, 0);
    }
#undef PHASE

    // C/D layout (measured m89/m91): col = lane&15, row = quad*4 + reg
#pragma unroll
    for (int qm = 0; qm < 2; qm++)
#pragma unroll
        for (int qn = 0; qn < 2; qn++)
#pragma unroll
            for (int mi = 0; mi < 4; mi++) {
                int mb = row0 + qm * 128 + wr * 64 + mi * 16 + q4 * 4;
#pragma unroll
                for (int ni = 0; ni < 2; ni++) {
                    int n = col0 + qn * 128 + wc * 32 + ni * 16 + fr;
#pragma unroll
                    for (int r = 0; r < 4; r++) {
                        int m = mb + r;
                        if (m < M) C[(size_t)m * Nn + n] = (_Float16)acc[qm][qn][mi][ni][r];
                    }
                }
            }
}

// ---------------------------------------------------------------------------
// fp16 MFMA GEMM (128x128, BK=32, dbuf) — kept for the small projection GEMM
// (Nn=256 is too narrow for the 256^2 8-phase kernel).
// EPI=1: store fp32 relu(C + bias[n]).
// ---------------------------------------------------------------------------
template <int EPI>
__global__ __launch_bounds__(256) void mfma_gemm_kernel(
    const _Float16* __restrict__ A, const _Float16* __restrict__ B,
    void* __restrict__ Cout, const float* __restrict__ bias,
    int M, int K, int Nn, int swz)
{
    __shared__ __align__(16) _Float16 sA[2][128 * 32];   // 2 x 8 KB
    __shared__ __align__(16) _Float16 sB[2][128 * 32];   // 2 x 8 KB

    int t = threadIdx.x;
    int bx = blockIdx.x, by = blockIdx.y;
    if (swz) {                       // gridDim.x == 16 only
        int id = by * 16 + bx;
        int xcd = id & 7, slot = id >> 3;
        bx = 2 * xcd + (slot & 1);
        by = slot >> 1;
    }
    int row0 = by * 128;
    int col0 = bx * 128;

    int s0 = t, s1 = t + 256;
    int m0 = s0 >> 2, k0 = (s0 & 3) * 8;
    int m1 = s1 >> 2, k1 = (s1 & 3) * 8;
    const _Float16* a0 = A + (size_t)(row0 + m0) * K + k0;
    const _Float16* a1 = A + (size_t)(row0 + m1) * K + k1;
    const _Float16* b0 = B + (size_t)(col0 + m0) * K + k0;
    const _Float16* b1 = B + (size_t)(col0 + m1) * K + k1;

    int w = t >> 6, lane = t & 63;
    int wm = (w & 1) * 64, wn = (w >> 1) * 64;
    int fr = lane & 15, quad = lane >> 4;

    auto stage = [&](int kt, int bsel) {
        _Float16* dA0 = &sA[bsel][(w * 64) * 8];
        _Float16* dA1 = &sA[bsel][(w * 64 + 256) * 8];
        _Float16* dB0 = &sB[bsel][(w * 64) * 8];
        _Float16* dB1 = &sB[bsel][(w * 64 + 256) * 8];
        __builtin_amdgcn_global_load_lds(
            (const __attribute__((address_space(1))) void*)(a0 + kt),
            (__attribute__((address_space(3))) void*)dA0, 16, 0, 0);
        __builtin_amdgcn_global_load_lds(
            (const __attribute__((address_space(1))) void*)(a1 + kt),
            (__attribute__((address_space(3))) void*)dA1, 16, 0, 0);
        __builtin_amdgcn_global_load_lds(
            (const __attribute__((address_space(1))) void*)(b0 + kt),
            (__attribute__((address_space(3))) void*)dB0, 16, 0, 0);
        __builtin_amdgcn_global_load_lds(
            (const __attribute__((address_space(1))) void*)(b1 + kt),
            (__attribute__((address_space(3))) void*)dB1, 16, 0, 0);
    };

    f32x4 acc[4][4];
#pragma unroll
    for (int i = 0; i < 4; i++)
#pragma unroll
        for (int j = 0; j < 4; j++) acc[i][j] = {0.f, 0.f, 0.f, 0.f};

    const int nIt = K / 32;
    stage(0, 0);
    __syncthreads();

    for (int it = 0; it < nIt; ++it) {
        int cb = it & 1;
        if (it + 1 < nIt) stage((it + 1) * 32, cb ^ 1);

        f16x8 fa[4], fb[4];
#pragma unroll
        for (int i = 0; i < 4; i++) {
            fa[i] = *(const f16x8*)&sA[cb][(wm + i * 16 + fr) * 32 + quad * 8];
            fb[i] = *(const f16x8*)&sB[cb][(wn + i * 16 + fr) * 32 + quad * 8];
        }
#pragma unroll
        for (int i = 0; i < 4; i++)
#pragma unroll
            for (int j = 0; j < 4; j++)
                acc[i][j] = __builtin_amdgcn_mfma_f32_16x16x32_f16(fa[i], fb[j], acc[i][j], 0, 0, 0);

        if (it + 1 < nIt) __syncthreads();
    }

    if (EPI == 0) {
        _Float16* C = (_Float16*)Cout;
#pragma unroll
        for (int i = 0; i < 4; i++) {
            int mbase = row0 + wm + i * 16 + quad * 4;
#pragma unroll
            for (int j = 0; j < 4; j++) {
                int n = col0 + wn + j * 16 + fr;
#pragma unroll
                for (int r = 0; r < 4; r++) {
                    int m = mbase + r;
                    if (m < M) C[(size_t)m * Nn + n] = (_Float16)acc[i][j][r];
                }
            }
        }
    } else {
        float* C = (float*)Cout;
        float bv[4];
#pragma unroll
        for (int j = 0; j < 4; j++) bv[j] = bias[col0 + wn + j * 16 + fr];
#pragma unroll
        for (int i = 0; i < 4; i++) {
            int mbase = row0 + wm + i * 16 + quad * 4;
#pragma unroll
            for (int j = 0; j < 4; j++) {
                int n = col0 + wn + j * 16 + fr;
#pragma unroll
                for (int r = 0; r < 4; r++) {
                    int m = mbase + r;
                    if (m < M) C[(size_t)m * Nn + n] = fmaxf(acc[i][j][r] + bv[j], 0.f);
                }
            }
        }
    }
}

// ---------------------------------------------------------------------------
// per-node attention coefficients from fp16 H
// ---------------------------------------------------------------------------
__global__ __launch_bounds__(256) void attn_kernel(
    const _Float16* __restrict__ H, const float* __restrict__ a_src,
    const float* __restrict__ a_dst, float* __restrict__ as_out,
    float* __restrict__ ad_out)
{
    int n = blockIdx.x;
    int t = threadIdx.x;
    int h = t >> 5, l = t & 31;
    f16x8 hv = *(const f16x8*)&H[(size_t)n * HC + h * HID + l * 8];
    const float* asp = a_src + h * HID + l * 8;
    const float* adp = a_dst + h * HID + l * 8;
    float sa = 0.f, sd = 0.f;
#pragma unroll
    for (int q = 0; q < 8; q++) {
        float v = (float)hv[q];
        sa = fmaf(v, asp[q], sa);
        sd = fmaf(v, adp[q], sd);
    }
#pragma unroll
    for (int o = 16; o > 0; o >>= 1) {
        sa += __shfl_xor(sa, o, 32);
        sd += __shfl_xor(sd, o, 32);
    }
    if (l == 0) { as_out[n * HEADS + h] = sa; ad_out[n * HEADS + h] = sd; }
}

// ---------------------------------------------------------------------------
// per-dst-node gather aggregation with segment softmax.  (unchanged R10 body)
// ---------------------------------------------------------------------------
template <int MODE>
__global__ __launch_bounds__(256) void agg_kernel(
    const _Float16* __restrict__ H, const float* __restrict__ as_,
    const float* __restrict__ ad_, const float* __restrict__ bias,
    const int* __restrict__ indptr, const int* __restrict__ sorted,
    const int* __restrict__ ei, _Float16* __restrict__ outh)
{
    __shared__ float m8[HEADS], d8[HEADS], adl[HEADS];
    __shared__ int   srcl[64];
    __shared__ float al[64][HEADS];
    __shared__ float red[HC];          // MODE 1 cross-head reduction

    int n = blockIdx.x;
    int t = threadIdx.x;

    if (n >= NNODES) {                 // pad rows for the next MFMA GEMM
        if (MODE == 0) {
            _Float16 z8[8] = {};
            *(f16x8*)&outh[(size_t)n * HC + t * 8] = *(f16x8*)z8;
        } else {
            outh[(size_t)n * HID + t] = (_Float16)0.f;
        }
        return;
    }

    int start = indptr[n];
    int deg = indptr[n + 1] - start;

    if (t < HEADS) adl[t] = ad_[n * HEADS + t];
    __syncthreads();

    int h = t >> 5, l = t & 31;
    float adh = adl[h];

    float mx = -1e30f;
    for (int j = l; j < deg; j += 32) {
        int e = sorted[start + j];
        int s = edge_src(ei, e);
        float v = as_[s * HEADS + h] + adh;
        v = (v >= 0.f) ? v : NEG_SLOPE * v;
        mx = fmaxf(mx, v);
    }
#pragma unroll
    for (int o = 16; o > 0; o >>= 1) mx = fmaxf(mx, __shfl_xor(mx, o, 32));

    float sm = 0.f;
    for (int j = l; j < deg; j += 32) {
        int e = sorted[start + j];
        int s = edge_src(ei, e);
        float v = as_[s * HEADS + h] + adh;
        v = (v >= 0.f) ? v : NEG_SLOPE * v;
        sm += expf(v - mx);
    }
#pragma unroll
    for (int o = 16; o > 0; o >>= 1) sm += __shfl_xor(sm, o, 32);
    if (l == 0) { m8[h] = mx; d8[h] = sm; }

    int hh = t >> 5, c8 = (t & 31) * 8;
    const size_t hoff = (size_t)hh * HID + c8;
    float acc[8] = {};
    for (int base = 0; base < deg; base += 64) {
        int cntc = min(64, deg - base);
        __syncthreads();
        if (t < cntc) srcl[t] = edge_src(ei, sorted[start + base + t]);
        __syncthreads();
        {
            int j = t & 63, h0 = t >> 6;
            if (j < cntc) {
#pragma unroll
                for (int q = 0; q < 2; q++) {
                    int hx = h0 + q * 4;
                    float v = as_[srcl[j] * HEADS + hx] + adl[hx];
                    v = (v >= 0.f) ? v : NEG_SLOPE * v;
                    al[j][hx] = expf(v - m8[hx]) / (d8[hx] + 1e-16f);
                }
            }
        }
        __syncthreads();
        int jj = 0;
        for (; jj + 3 < cntc; jj += 4) {
            int sx0 = srcl[jj + 0], sx1 = srcl[jj + 1];
            int sx2 = srcl[jj + 2], sx3 = srcl[jj + 3];
            f16x8 h0v = *(const f16x8*)&H[(size_t)sx0 * HC + hoff];
            f16x8 h1v = *(const f16x8*)&H[(size_t)sx1 * HC + hoff];
            f16x8 h2v = *(const f16x8*)&H[(size_t)sx2 * HC + hoff];
            f16x8 h3v = *(const f16x8*)&H[(size_t)sx3 * HC + hoff];
            float a0 = al[jj + 0][hh], a1 = al[jj + 1][hh];
            float a2 = al[jj + 2][hh], a3 = al[jj + 3][hh];
#pragma unroll
            for (int q = 0; q < 8; q++) acc[q] = fmaf(a0, (float)h0v[q], acc[q]);
#pragma unroll
            for (int q = 0; q < 8; q++) acc[q] = fmaf(a1, (float)h1v[q], acc[q]);
#pragma unroll
            for (int q = 0; q < 8; q++) acc[q] = fmaf(a2, (float)h2v[q], acc[q]);
#pragma unroll
            for (int q = 0; q < 8; q++) acc[q] = fmaf(a3, (float)h3v[q], acc[q]);
        }
        for (; jj < cntc; jj++) {
            int s = srcl[jj];
            f16x8 hv = *(const f16x8*)&H[(size_t)s * HC + hoff];
            float a = al[jj][hh];
#pragma unroll
            for (int q = 0; q < 8; q++)
                acc[q] = fmaf(a, (float)hv[q], acc[q]);
        }
    }

    if (MODE == 0) {
        _Float16 o8[8];
#pragma unroll
        for (int q = 0; q < 8; q++) {
            float v = acc[q] + bias[hoff + q];
            v = (v > 0.f) ? v : expm1f(v);          // ELU (alpha=1)
            o8[q] = (_Float16)v;
        }
        *(f16x8*)&outh[(size_t)n * HC + hoff] = *(f16x8*)o8;
    } else {
#pragma unroll
        for (int q = 0; q < 8; q++) red[hoff + q] = acc[q];
        __syncthreads();
        float s = 0.f;
#pragma unroll
        for (int h2 = 0; h2 < HEADS; h2++) s += red[h2 * HID + t];
        outh[(size_t)n * HID + t] = (_Float16)(s * 0.125f + bias[t]);
    }
}

// ---------------------------------------------------------------------------
extern "C" void kernel_launch(void* const* d_in, const int* in_sizes, int n_in,
                              void* d_out, int out_size, void* d_ws, size_t ws_size,
                              hipStream_t stream)
{
    const float* x      = (const float*)d_in[0];
    const int*   ei     = (const int*)  d_in[1];
    const float* W1     = (const float*)d_in[2];
    const float* a_src1 = (const float*)d_in[3];
    const float* a_dst1 = (const float*)d_in[4];
    const float* b1     = (const float*)d_in[5];
    const float* W2     = (const float*)d_in[6];
    const float* a_src2 = (const float*)d_in[7];
    const float* a_dst2 = (const float*)d_in[8];
    const float* b2     = (const float*)d_in[9];
    const float* Wp     = (const float*)d_in[10];
    const float* bp     = (const float*)d_in[11];
    float* out = (float*)d_out;

    char* ws = (char*)d_ws;
    size_t off = 0;
    auto alloc = [&](size_t bytes) -> char* {
        char* p = ws + off;
        off += (bytes + 255) & ~(size_t)255;
        return p;
    };
    _Float16* Hbuf = (_Float16*)alloc((size_t)NNODES * HC * 2);          // 41 MB (H1, then H2)
    _Float16* A2   = (_Float16*)alloc((size_t)MPAD * HC * 2);            // 41.9 MB
    _Float16* W1t  = (_Float16*)alloc((size_t)HC * IN_DIM * 2);          // 3.1 MB
    _Float16* W2t  = (_Float16*)alloc((size_t)HC * HC * 2);              // 8.4 MB
    _Float16* Wpt  = (_Float16*)alloc((size_t)HID * HID * 2);            // 128 KB
    _Float16* xh   = (_Float16*)alloc((size_t)MPAD * IN_DIM * 2);        // 15.7 MB
    _Float16* out2h = (_Float16*)alloc((size_t)MPAD * HID * 2);          // 5.2 MB
    float* asad   = (float*)alloc((size_t)4 * NNODES * HEADS * sizeof(float));
    float* as1 = asad;
    float* ad1 = asad + (size_t)NNODES * HEADS;
    float* as2 = asad + (size_t)2 * NNODES * HEADS;
    float* ad2 = asad + (size_t)3 * NNODES * HEADS;
    int*   cntcur = (int*)alloc((size_t)2 * NNODES * sizeof(int));   // cnt | cur contiguous
    int*   cnt = cntcur;
    int*   cur = cntcur + NNODES;
    int*   indptr = (int*)  alloc((size_t)(NNODES + 1) * sizeof(int));
    int*   sorted = (int*)  alloc((size_t)E_TOT * sizeof(int));

    // --- one memset for cnt+cur, then fused prep (cvt + count + 3 transposes)
    hipMemsetAsync(cntcur, 0, (size_t)2 * NNODES * sizeof(int), stream);
    prep_kernel<<<PREP_BLK, 256, 0, stream>>>(x, xh, ei, cnt,
                                              W1, W1t, W2, W2t, Wp, Wpt);
    scan_kernel<<<1, 1024, 0, stream>>>(cnt, indptr);
    scatter_kernel<<<(E_TOT + 255) / 256, 256, 0, stream>>>(ei, indptr, cur, sorted);

    dim3 g8(HC / 256, MPAD / 256);   // 8 x 40 = 320 blocks (nwg % 8 == 0)

    // Layer 1: H1 = x @ W1 (8-phase 256^2 fp16 MFMA)
    gemm8p_kernel<<<g8, 512, 0, stream>>>(xh, W1t, Hbuf, NNODES, IN_DIM, HC);
    attn_kernel<<<NNODES, 256, 0, stream>>>(Hbuf, a_src1, a_dst1, as1, ad1);
    agg_kernel<0><<<MPAD, 256, 0, stream>>>(Hbuf, as1, ad1, b1, indptr, sorted, ei, A2);

    // Layer 2: H2 = elu_agg @ W2 (8-phase 256^2 fp16 MFMA)
    gemm8p_kernel<<<g8, 512, 0, stream>>>(A2, W2t, Hbuf, NNODES, HC, HC);
    attn_kernel<<<NNODES, 256, 0, stream>>>(Hbuf, a_src2, a_dst2, as2, ad2);
    agg_kernel<1><<<MPAD, 256, 0, stream>>>(Hbuf, as2, ad2, b2, indptr, sorted, ei, out2h);

    // Projection + ReLU (128^2 fp16 MFMA, bias+relu fp32 epilogue)
    dim3 gProj(HID / 128, MPAD / 128);   // 2 x 80
    mfma_gemm_kernel<1><<<gProj, 256, 0, stream>>>(out2h, Wpt, out, bp,
                                                   NNODES, HID, HID, 0);
}

// Round 2
// 412.996 us; speedup vs baseline: 1.1658x; 1.1658x over previous
//
#include <hip/hip_runtime.h>
#include <cstdint>
#include <cstddef>

#define IN_DIM  768
#define NNODES  10000
#define MPAD    10240        // 32 * 320 (gemm8p) and 80 * 128 (proj GEMM)
#define NEDGES  80000
#define E_TOT   90000        // edges + self loops
#define HEADS   8
#define HID     256
#define HC      2048         // HEADS*HID
#define NEG_SLOPE 0.2f

// prep_kernel block ranges (256 threads each)
#define CVT_BLK  ((MPAD * IN_DIM / 4) / 256)          // 7680
#define CNT_BLK  ((E_TOT + 255) / 256)                // 352
#define T1_BLK   ((HC / 32) * (IN_DIM / 32))          // 1536
#define T2_BLK   ((HC / 32) * (HC / 32))              // 4096
#define TP_BLK   ((HID / 32) * (HID / 32))            // 64
#define PREP_BLK (CVT_BLK + CNT_BLK + T1_BLK + T2_BLK + TP_BLK)

typedef _Float16 __attribute__((ext_vector_type(8))) f16x8;
typedef float    __attribute__((ext_vector_type(4))) f32x4;

// ---------------------------------------------------------------------------
// edge helpers: edge ids [0,NEDGES) are real edges, [NEDGES,E_TOT) self loops
// ---------------------------------------------------------------------------
__device__ __forceinline__ int edge_src(const int* __restrict__ ei, int e) {
    return (e < NEDGES) ? ei[e] : (e - NEDGES);
}
__device__ __forceinline__ int edge_dst(const int* __restrict__ ei, int e) {
    return (e < NEDGES) ? ei[NEDGES + e] : (e - NEDGES);
}

// ---------------------------------------------------------------------------
// fused preprocessing (R9-proven): cvt + edge count + 3 weight transposes
// ---------------------------------------------------------------------------
__device__ __forceinline__ void tcvt_body(
    const float* __restrict__ W, _Float16* __restrict__ T,
    int K, int N, int bx, int by, int t)
{
    __shared__ float tile[32][33];
    int tx = t & 31, ty = t >> 5;   // 32 x 8
#pragma unroll
    for (int q = 0; q < 4; q++)
        tile[ty + q * 8][tx] = W[(size_t)(by * 32 + ty + q * 8) * N + bx * 32 + tx];
    __syncthreads();
#pragma unroll
    for (int q = 0; q < 4; q++) {
        float v = tile[tx][ty + q * 8];
        T[(size_t)(bx * 32 + ty + q * 8) * K + by * 32 + tx] = (_Float16)v;
    }
}

__global__ __launch_bounds__(256) void prep_kernel(
    const float* __restrict__ x, _Float16* __restrict__ xh,
    const int* __restrict__ ei, int* __restrict__ cnt,
    const float* __restrict__ W1, _Float16* __restrict__ W1t,
    const float* __restrict__ W2, _Float16* __restrict__ W2t,
    const float* __restrict__ Wp, _Float16* __restrict__ Wpt)
{
    int b = blockIdx.x;
    int t = threadIdx.x;
    if (b < CVT_BLK) {
        int i = b * 256 + t;
        size_t e = (size_t)i * 4;
        int r = (int)(e / IN_DIM);
        float4 v = (r < NNODES) ? *(const float4*)(x + e)
                                : make_float4(0.f, 0.f, 0.f, 0.f);
        _Float16 h4[4] = {(_Float16)v.x, (_Float16)v.y, (_Float16)v.z, (_Float16)v.w};
        *(ushort4*)(xh + e) = *(ushort4*)h4;
    } else if (b < CVT_BLK + CNT_BLK) {
        int e = (b - CVT_BLK) * 256 + t;
        if (e < E_TOT) atomicAdd(&cnt[edge_dst(ei, e)], 1);
    } else if (b < CVT_BLK + CNT_BLK + T1_BLK) {
        int idx = b - (CVT_BLK + CNT_BLK);
        tcvt_body(W1, W1t, IN_DIM, HC, idx % (HC / 32), idx / (HC / 32), t);
    } else if (b < CVT_BLK + CNT_BLK + T1_BLK + T2_BLK) {
        int idx = b - (CVT_BLK + CNT_BLK + T1_BLK);
        tcvt_body(W2, W2t, HC, HC, idx % (HC / 32), idx / (HC / 32), t);
    } else {
        int idx = b - (CVT_BLK + CNT_BLK + T1_BLK + T2_BLK);
        tcvt_body(Wp, Wpt, HID, HID, idx % (HID / 32), idx / (HID / 32), t);
    }
}

// ---------------------------------------------------------------------------
// CSR: scan + scatter (count fused into prep_kernel)
// ---------------------------------------------------------------------------
__global__ void scan_kernel(const int* __restrict__ cnt, int* __restrict__ indptr) {
    __shared__ int sums[1024];
    const int CH = 10;
    int t = threadIdx.x;
    int base = t * CH;
    int s = 0;
#pragma unroll
    for (int i = 0; i < CH; i++) { int idx = base + i; if (idx < NNODES) s += cnt[idx]; }
    sums[t] = s;
    __syncthreads();
    for (int off = 1; off < 1024; off <<= 1) {
        int v = (t >= off) ? sums[t - off] : 0;
        __syncthreads();
        sums[t] += v;
        __syncthreads();
    }
    int run = (t == 0) ? 0 : sums[t - 1];
#pragma unroll
    for (int i = 0; i < CH; i++) {
        int idx = base + i;
        if (idx < NNODES) { indptr[idx] = run; run += cnt[idx]; }
    }
    if (t == 0) indptr[NNODES] = E_TOT;
}

__global__ void scatter_kernel(const int* __restrict__ ei, const int* __restrict__ indptr,
                               int* __restrict__ cur, int* __restrict__ sorted) {
    int e = blockIdx.x * 256 + threadIdx.x;
    if (e < E_TOT) {
        int d = edge_dst(ei, e);
        int pos = atomicAdd(&cur[d], 1);
        sorted[indptr[d] + pos] = e;
    }
}

// ---------------------------------------------------------------------------
// 8-phase 320x256 fp16 MFMA GEMM (m201 template, tail-free grid):
//   C[M,Nn] = A[Mpad,K] @ B[Nn,K]^T,  fp16 out, guard m < M.
// BM=320 -> grid = (Nn/256) x (Mpad/320) = 8 x 32 = 256 blocks = exactly one
// full chip round (fixes round-1's 2-round makespan: 320 blocks @ 1 blk/CU).
// BK=64, 512 thr = 8 waves (2M x 4N), per-wave output 160x64.
// LDS 144 KiB: lds[2][A 320x64 | B 256x64], A halves of 160 rows, B of 128.
// T2 swizzle: 16B slot s of row r holds k-slot (s ^ (r&7)) — pre-swizzled
// global source (linear global_load_lds dest, rule #21) + swizzled ds_read.
// Staging: 9 loads/tile (A q0..q4, B q0..q3), spread {Aq0,Aq1 | Aq2,Bq0,Bq1 |
// Aq3,Aq4 | Bq2,Bq3} over the 4 phases; read order p1=(0,0) p2=(1,0) p3=(0,1)
// p4=(1,1) gives every half issue->first-read distance >= 3 phases.
// EXACT per-phase vmcnt from queue tracking (round-1's uniform vmcnt(4)
// over-waited on loads issued 2 phases prior — the measured stall):
//   steady state p1=vmcnt(6), p2=vmcnt(7), p3=vmcnt(7), p4=none;
//   final tile 4/2/0/none.  T5: setprio(1) around MFMA cluster.
// Requires K%64==0, K/64>=2, Nn%256==0, Mpad%320==0, nwg%8==0.
// ---------------------------------------------------------------------------
__global__ __launch_bounds__(512, 2) void gemm8p_kernel(
    const _Float16* __restrict__ A, const _Float16* __restrict__ B,
    _Float16* __restrict__ C, int M, int K, int Nn)
{
    __shared__ __align__(16) _Float16 lds[2][36864];   // 2 x (20480 A + 16384 B) = 144 KiB

    const int t = threadIdx.x;
    const int w = t >> 6, lane = t & 63;
    const int fr = lane & 15, q4 = lane >> 4;
    const int wr = w >> 2, wc = w & 3;        // 2 x 4 wave grid

    // bijective XCD chunk swizzle (nwg == 256, %8 == 0)
    const int nwgx = gridDim.x;
    int wg = blockIdx.y * nwgx + blockIdx.x;
    const int cpx = (nwgx * gridDim.y) >> 3;
    wg = (wg & 7) * cpx + (wg >> 3);
    const int row0 = (wg / nwgx) * 320;
    const int col0 = (wg % nwgx) * 256;

    // staging: load q covers rows [q*64, q*64+64), thread t -> row q*64 + (t>>3),
    // 16B slot t&7; swizzled global column = ((t&7) ^ (row&7)) * 8 elements.
    const int rowt = t >> 3;
    const int scol = ((t & 7) ^ (rowt & 7)) << 3;
    const _Float16* baseA = A + (size_t)(row0 + rowt) * K + scol;
    const _Float16* baseB = B + (size_t)(col0 + rowt) * K + scol;
    const int dstw = w * 512;                 // wave-uniform elem offset in a 4096-el load block

    auto stageA = [&](int q, int kel, int bb) {
        __builtin_amdgcn_global_load_lds(
            (const __attribute__((address_space(1))) void*)(baseA + (size_t)q * 64 * K + kel),
            (__attribute__((address_space(3))) void*)&lds[bb][q * 4096 + dstw], 16, 0, 0);
    };
    auto stageB = [&](int q, int kel, int bb) {
        __builtin_amdgcn_global_load_lds(
            (const __attribute__((address_space(1))) void*)(baseB + (size_t)q * 64 * K + kel),
            (__attribute__((address_space(3))) void*)&lds[bb][20480 + q * 4096 + dstw], 16, 0, 0);
    };

    f32x4 acc[2][2][5][2];
#pragma unroll
    for (int qm = 0; qm < 2; qm++)
#pragma unroll
        for (int qn = 0; qn < 2; qn++)
#pragma unroll
            for (int mi = 0; mi < 5; mi++)
#pragma unroll
                for (int ni = 0; ni < 2; ni++)
                    acc[qm][qn][mi][ni] = {0.f, 0.f, 0.f, 0.f};

// one phase: quadrant (QM,QN) of the tile in buf BB.
// STAGE_STMT issues next-tile loads; WAIT_STMT is the exact vmcnt bound.
#define PHASE(QM, QN, BB, STAGE_STMT, WAIT_STMT)                                \
    do {                                                                        \
        f16x8 fa[5][2], fb[2][2];                                               \
        _Pragma("unroll")                                                       \
        for (int mi = 0; mi < 5; mi++) {                                        \
            _Pragma("unroll")                                                   \
            for (int ks = 0; ks < 2; ks++) {                                    \
                int lr = wr * 80 + mi * 16 + fr;                                \
                int sl = ((ks << 2) | q4) ^ (fr & 7);                           \
                fa[mi][ks] = *(const f16x8*)&lds[BB][(QM) * 10240 + (lr << 6) + (sl << 3)]; \
            }                                                                   \
        }                                                                       \
        _Pragma("unroll")                                                       \
        for (int ni = 0; ni < 2; ni++) {                                        \
            _Pragma("unroll")                                                   \
            for (int ks = 0; ks < 2; ks++) {                                    \
                int lr = wc * 32 + ni * 16 + fr;                                \
                int sl = ((ks << 2) | q4) ^ (fr & 7);                           \
                fb[ni][ks] = *(const f16x8*)&lds[BB][20480 + (QN) * 8192 + (lr << 6) + (sl << 3)]; \
            }                                                                   \
        }                                                                       \
        STAGE_STMT;                                                             \
        WAIT_STMT;                                                              \
        __builtin_amdgcn_s_barrier();                                           \
        asm volatile("s_waitcnt lgkmcnt(0)" ::: "memory");                      \
        __builtin_amdgcn_sched_barrier(0);                                      \
        __builtin_amdgcn_s_setprio(1);                                          \
        _Pragma("unroll")                                                       \
        for (int ks = 0; ks < 2; ks++) {                                        \
            _Pragma("unroll")                                                   \
            for (int mi = 0; mi < 5; mi++) {                                    \
                _Pragma("unroll")                                               \
                for (int ni = 0; ni < 2; ni++)                                  \
                    acc[QM][QN][mi][ni] = __builtin_amdgcn_mfma_f32_16x16x32_f16(\
                        fa[mi][ks], fb[ni][ks], acc[QM][QN][mi][ni], 0, 0, 0);  \
            }                                                                   \
        }                                                                       \
        __builtin_amdgcn_s_setprio(0);                                          \
        __builtin_amdgcn_sched_barrier(0);                                      \
        __builtin_amdgcn_s_barrier();                                           \
    } while (0)

    // prologue: tile 0 fully staged, one-time drain
#pragma unroll
    for (int q = 0; q < 5; q++) stageA(q, 0, 0);
#pragma unroll
    for (int q = 0; q < 4; q++) stageB(q, 0, 0);
    asm volatile("s_waitcnt vmcnt(0)" ::: "memory");
    __builtin_amdgcn_s_barrier();

    const int nT = K >> 6;
    int t0 = 0;
    for (; t0 < nT - 1; ++t0) {
        int bb = t0 & 1;
        int bn = bb ^ 1;
        int k1 = (t0 + 1) << 6;
        PHASE(0, 0, bb,
              { stageA(0, k1, bn); stageA(1, k1, bn); },
              asm volatile("s_waitcnt vmcnt(6)" ::: "memory"));
        PHASE(1, 0, bb,
              { stageA(2, k1, bn); stageB(0, k1, bn); stageB(1, k1, bn); },
              asm volatile("s_waitcnt vmcnt(7)" ::: "memory"));
        PHASE(0, 1, bb,
              { stageA(3, k1, bn); stageA(4, k1, bn); },
              asm volatile("s_waitcnt vmcnt(7)" ::: "memory"));
        PHASE(1, 1, bb,
              { stageB(2, k1, bn); stageB(3, k1, bn); },
              ((void)0));
    }
    {   // final tile: no prefetch; exact residual drains
        int bb = t0 & 1;
        PHASE(0, 0, bb, ((void)0), asm volatile("s_waitcnt vmcnt(4)" ::: "memory"));
        PHASE(1, 0, bb, ((void)0), asm volatile("s_waitcnt vmcnt(2)" ::: "memory"));
        PHASE(0, 1, bb, ((void)0), asm volatile("s_waitcnt vmcnt(0)" ::: "memory"));
        PHASE(1, 1, bb, ((void)0), ((void)0));
    }
#undef PHASE

    // C/D layout (measured m89/m91): col = lane&15, row = quad*4 + reg
#pragma unroll
    for (int qm = 0; qm < 2; qm++)
#pragma unroll
        for (int qn = 0; qn < 2; qn++)
#pragma unroll
            for (int mi = 0; mi < 5; mi++) {
                int mb = row0 + qm * 160 + wr * 80 + mi * 16 + q4 * 4;
#pragma unroll
                for (int ni = 0; ni < 2; ni++) {
                    int n = col0 + qn * 128 + wc * 32 + ni * 16 + fr;
#pragma unroll
                    for (int r = 0; r < 4; r++) {
                        int m = mb + r;
                        if (m < M) C[(size_t)m * Nn + n] = (_Float16)acc[qm][qn][mi][ni][r];
                    }
                }
            }
}

// ---------------------------------------------------------------------------
// fp16 MFMA GEMM (128x128, BK=32, dbuf) — kept for the small projection GEMM
// (Nn=256 is too narrow for the 8-phase kernel).  EPI=1: fp32 relu(C + bias).
// ---------------------------------------------------------------------------
template <int EPI>
__global__ __launch_bounds__(256) void mfma_gemm_kernel(
    const _Float16* __restrict__ A, const _Float16* __restrict__ B,
    void* __restrict__ Cout, const float* __restrict__ bias,
    int M, int K, int Nn, int swz)
{
    __shared__ __align__(16) _Float16 sA[2][128 * 32];   // 2 x 8 KB
    __shared__ __align__(16) _Float16 sB[2][128 * 32];   // 2 x 8 KB

    int t = threadIdx.x;
    int bx = blockIdx.x, by = blockIdx.y;
    if (swz) {                       // gridDim.x == 16 only
        int id = by * 16 + bx;
        int xcd = id & 7, slot = id >> 3;
        bx = 2 * xcd + (slot & 1);
        by = slot >> 1;
    }
    int row0 = by * 128;
    int col0 = bx * 128;

    int s0 = t, s1 = t + 256;
    int m0 = s0 >> 2, k0 = (s0 & 3) * 8;
    int m1 = s1 >> 2, k1 = (s1 & 3) * 8;
    const _Float16* a0 = A + (size_t)(row0 + m0) * K + k0;
    const _Float16* a1 = A + (size_t)(row0 + m1) * K + k1;
    const _Float16* b0 = B + (size_t)(col0 + m0) * K + k0;
    const _Float16* b1 = B + (size_t)(col0 + m1) * K + k1;

    int w = t >> 6, lane = t & 63;
    int wm = (w & 1) * 64, wn = (w >> 1) * 64;
    int fr = lane & 15, quad = lane >> 4;

    auto stage = [&](int kt, int bsel) {
        _Float16* dA0 = &sA[bsel][(w * 64) * 8];
        _Float16* dA1 = &sA[bsel][(w * 64 + 256) * 8];
        _Float16* dB0 = &sB[bsel][(w * 64) * 8];
        _Float16* dB1 = &sB[bsel][(w * 64 + 256) * 8];
        __builtin_amdgcn_global_load_lds(
            (const __attribute__((address_space(1))) void*)(a0 + kt),
            (__attribute__((address_space(3))) void*)dA0, 16, 0, 0);
        __builtin_amdgcn_global_load_lds(
            (const __attribute__((address_space(1))) void*)(a1 + kt),
            (__attribute__((address_space(3))) void*)dA1, 16, 0, 0);
        __builtin_amdgcn_global_load_lds(
            (const __attribute__((address_space(1))) void*)(b0 + kt),
            (__attribute__((address_space(3))) void*)dB0, 16, 0, 0);
        __builtin_amdgcn_global_load_lds(
            (const __attribute__((address_space(1))) void*)(b1 + kt),
            (__attribute__((address_space(3))) void*)dB1, 16, 0, 0);
    };

    f32x4 acc[4][4];
#pragma unroll
    for (int i = 0; i < 4; i++)
#pragma unroll
        for (int j = 0; j < 4; j++) acc[i][j] = {0.f, 0.f, 0.f, 0.f};

    const int nIt = K / 32;
    stage(0, 0);
    __syncthreads();

    for (int it = 0; it < nIt; ++it) {
        int cb = it & 1;
        if (it + 1 < nIt) stage((it + 1) * 32, cb ^ 1);

        f16x8 fa[4], fb[4];
#pragma unroll
        for (int i = 0; i < 4; i++) {
            fa[i] = *(const f16x8*)&sA[cb][(wm + i * 16 + fr) * 32 + quad * 8];
            fb[i] = *(const f16x8*)&sB[cb][(wn + i * 16 + fr) * 32 + quad * 8];
        }
#pragma unroll
        for (int i = 0; i < 4; i++)
#pragma unroll
            for (int j = 0; j < 4; j++)
                acc[i][j] = __builtin_amdgcn_mfma_f32_16x16x32_f16(fa[i], fb[j], acc[i][j], 0, 0, 0);

        if (it + 1 < nIt) __syncthreads();
    }

    if (EPI == 0) {
        _Float16* C = (_Float16*)Cout;
#pragma unroll
        for (int i = 0; i < 4; i++) {
            int mbase = row0 + wm + i * 16 + quad * 4;
#pragma unroll
            for (int j = 0; j < 4; j++) {
                int n = col0 + wn + j * 16 + fr;
#pragma unroll
                for (int r = 0; r < 4; r++) {
                    int m = mbase + r;
                    if (m < M) C[(size_t)m * Nn + n] = (_Float16)acc[i][j][r];
                }
            }
        }
    } else {
        float* C = (float*)Cout;
        float bv[4];
#pragma unroll
        for (int j = 0; j < 4; j++) bv[j] = bias[col0 + wn + j * 16 + fr];
#pragma unroll
        for (int i = 0; i < 4; i++) {
            int mbase = row0 + wm + i * 16 + quad * 4;
#pragma unroll
            for (int j = 0; j < 4; j++) {
                int n = col0 + wn + j * 16 + fr;
#pragma unroll
                for (int r = 0; r < 4; r++) {
                    int m = mbase + r;
                    if (m < M) C[(size_t)m * Nn + n] = fmaxf(acc[i][j][r] + bv[j], 0.f);
                }
            }
        }
    }
}

// ---------------------------------------------------------------------------
// per-node attention coefficients from fp16 H
// ---------------------------------------------------------------------------
__global__ __launch_bounds__(256) void attn_kernel(
    const _Float16* __restrict__ H, const float* __restrict__ a_src,
    const float* __restrict__ a_dst, float* __restrict__ as_out,
    float* __restrict__ ad_out)
{
    int n = blockIdx.x;
    int t = threadIdx.x;
    int h = t >> 5, l = t & 31;
    f16x8 hv = *(const f16x8*)&H[(size_t)n * HC + h * HID + l * 8];
    const float* asp = a_src + h * HID + l * 8;
    const float* adp = a_dst + h * HID + l * 8;
    float sa = 0.f, sd = 0.f;
#pragma unroll
    for (int q = 0; q < 8; q++) {
        float v = (float)hv[q];
        sa = fmaf(v, asp[q], sa);
        sd = fmaf(v, adp[q], sd);
    }
#pragma unroll
    for (int o = 16; o > 0; o >>= 1) {
        sa += __shfl_xor(sa, o, 32);
        sd += __shfl_xor(sd, o, 32);
    }
    if (l == 0) { as_out[n * HEADS + h] = sa; ad_out[n * HEADS + h] = sd; }
}

// ---------------------------------------------------------------------------
// per-dst-node gather aggregation with segment softmax.  (unchanged R10 body)
// ---------------------------------------------------------------------------
template <int MODE>
__global__ __launch_bounds__(256) void agg_kernel(
    const _Float16* __restrict__ H, const float* __restrict__ as_,
    const float* __restrict__ ad_, const float* __restrict__ bias,
    const int* __restrict__ indptr, const int* __restrict__ sorted,
    const int* __restrict__ ei, _Float16* __restrict__ outh)
{
    __shared__ float m8[HEADS], d8[HEADS], adl[HEADS];
    __shared__ int   srcl[64];
    __shared__ float al[64][HEADS];
    __shared__ float red[HC];          // MODE 1 cross-head reduction

    int n = blockIdx.x;
    int t = threadIdx.x;

    if (n >= NNODES) {                 // pad rows for the next MFMA GEMM
        if (MODE == 0) {
            _Float16 z8[8] = {};
            *(f16x8*)&outh[(size_t)n * HC + t * 8] = *(f16x8*)z8;
        } else {
            outh[(size_t)n * HID + t] = (_Float16)0.f;
        }
        return;
    }

    int start = indptr[n];
    int deg = indptr[n + 1] - start;

    if (t < HEADS) adl[t] = ad_[n * HEADS + t];
    __syncthreads();

    int h = t >> 5, l = t & 31;
    float adh = adl[h];

    float mx = -1e30f;
    for (int j = l; j < deg; j += 32) {
        int e = sorted[start + j];
        int s = edge_src(ei, e);
        float v = as_[s * HEADS + h] + adh;
        v = (v >= 0.f) ? v : NEG_SLOPE * v;
        mx = fmaxf(mx, v);
    }
#pragma unroll
    for (int o = 16; o > 0; o >>= 1) mx = fmaxf(mx, __shfl_xor(mx, o, 32));

    float sm = 0.f;
    for (int j = l; j < deg; j += 32) {
        int e = sorted[start + j];
        int s = edge_src(ei, e);
        float v = as_[s * HEADS + h] + adh;
        v = (v >= 0.f) ? v : NEG_SLOPE * v;
        sm += expf(v - mx);
    }
#pragma unroll
    for (int o = 16; o > 0; o >>= 1) sm += __shfl_xor(sm, o, 32);
    if (l == 0) { m8[h] = mx; d8[h] = sm; }

    int hh = t >> 5, c8 = (t & 31) * 8;
    const size_t hoff = (size_t)hh * HID + c8;
    float acc[8] = {};
    for (int base = 0; base < deg; base += 64) {
        int cntc = min(64, deg - base);
        __syncthreads();
        if (t < cntc) srcl[t] = edge_src(ei, sorted[start + base + t]);
        __syncthreads();
        {
            int j = t & 63, h0 = t >> 6;
            if (j < cntc) {
#pragma unroll
                for (int q = 0; q < 2; q++) {
                    int hx = h0 + q * 4;
                    float v = as_[srcl[j] * HEADS + hx] + adl[hx];
                    v = (v >= 0.f) ? v : NEG_SLOPE * v;
                    al[j][hx] = expf(v - m8[hx]) / (d8[hx] + 1e-16f);
                }
            }
        }
        __syncthreads();
        int jj = 0;
        for (; jj + 3 < cntc; jj += 4) {
            int sx0 = srcl[jj + 0], sx1 = srcl[jj + 1];
            int sx2 = srcl[jj + 2], sx3 = srcl[jj + 3];
            f16x8 h0v = *(const f16x8*)&H[(size_t)sx0 * HC + hoff];
            f16x8 h1v = *(const f16x8*)&H[(size_t)sx1 * HC + hoff];
            f16x8 h2v = *(const f16x8*)&H[(size_t)sx2 * HC + hoff];
            f16x8 h3v = *(const f16x8*)&H[(size_t)sx3 * HC + hoff];
            float a0 = al[jj + 0][hh], a1 = al[jj + 1][hh];
            float a2 = al[jj + 2][hh], a3 = al[jj + 3][hh];
#pragma unroll
            for (int q = 0; q < 8; q++) acc[q] = fmaf(a0, (float)h0v[q], acc[q]);
#pragma unroll
            for (int q = 0; q < 8; q++) acc[q] = fmaf(a1, (float)h1v[q], acc[q]);
#pragma unroll
            for (int q = 0; q < 8; q++) acc[q] = fmaf(a2, (float)h2v[q], acc[q]);
#pragma unroll
            for (int q = 0; q < 8; q++) acc[q] = fmaf(a3, (float)h3v[q], acc[q]);
        }
        for (; jj < cntc; jj++) {
            int s = srcl[jj];
            f16x8 hv = *(const f16x8*)&H[(size_t)s * HC + hoff];
            float a = al[jj][hh];
#pragma unroll
            for (int q = 0; q < 8; q++)
                acc[q] = fmaf(a, (float)hv[q], acc[q]);
        }
    }

    if (MODE == 0) {
        _Float16 o8[8];
#pragma unroll
        for (int q = 0; q < 8; q++) {
            float v = acc[q] + bias[hoff + q];
            v = (v > 0.f) ? v : expm1f(v);          // ELU (alpha=1)
            o8[q] = (_Float16)v;
        }
        *(f16x8*)&outh[(size_t)n * HC + hoff] = *(f16x8*)o8;
    } else {
#pragma unroll
        for (int q = 0; q < 8; q++) red[hoff + q] = acc[q];
        __syncthreads();
        float s = 0.f;
#pragma unroll
        for (int h2 = 0; h2 < HEADS; h2++) s += red[h2 * HID + t];
        outh[(size_t)n * HID + t] = (_Float16)(s * 0.125f + bias[t]);
    }
}

// ---------------------------------------------------------------------------
extern "C" void kernel_launch(void* const* d_in, const int* in_sizes, int n_in,
                              void* d_out, int out_size, void* d_ws, size_t ws_size,
                              hipStream_t stream)
{
    const float* x      = (const float*)d_in[0];
    const int*   ei     = (const int*)  d_in[1];
    const float* W1     = (const float*)d_in[2];
    const float* a_src1 = (const float*)d_in[3];
    const float* a_dst1 = (const float*)d_in[4];
    const float* b1     = (const float*)d_in[5];
    const float* W2     = (const float*)d_in[6];
    const float* a_src2 = (const float*)d_in[7];
    const float* a_dst2 = (const float*)d_in[8];
    const float* b2     = (const float*)d_in[9];
    const float* Wp     = (const float*)d_in[10];
    const float* bp     = (const float*)d_in[11];
    float* out = (float*)d_out;

    char* ws = (char*)d_ws;
    size_t off = 0;
    auto alloc = [&](size_t bytes) -> char* {
        char* p = ws + off;
        off += (bytes + 255) & ~(size_t)255;
        return p;
    };
    _Float16* Hbuf = (_Float16*)alloc((size_t)NNODES * HC * 2);          // 41 MB (H1, then H2)
    _Float16* A2   = (_Float16*)alloc((size_t)MPAD * HC * 2);            // 41.9 MB
    _Float16* W1t  = (_Float16*)alloc((size_t)HC * IN_DIM * 2);          // 3.1 MB
    _Float16* W2t  = (_Float16*)alloc((size_t)HC * HC * 2);              // 8.4 MB
    _Float16* Wpt  = (_Float16*)alloc((size_t)HID * HID * 2);            // 128 KB
    _Float16* xh   = (_Float16*)alloc((size_t)MPAD * IN_DIM * 2);        // 15.7 MB
    _Float16* out2h = (_Float16*)alloc((size_t)MPAD * HID * 2);          // 5.2 MB
    float* asad   = (float*)alloc((size_t)4 * NNODES * HEADS * sizeof(float));
    float* as1 = asad;
    float* ad1 = asad + (size_t)NNODES * HEADS;
    float* as2 = asad + (size_t)2 * NNODES * HEADS;
    float* ad2 = asad + (size_t)3 * NNODES * HEADS;
    int*   cntcur = (int*)alloc((size_t)2 * NNODES * sizeof(int));   // cnt | cur contiguous
    int*   cnt = cntcur;
    int*   cur = cntcur + NNODES;
    int*   indptr = (int*)  alloc((size_t)(NNODES + 1) * sizeof(int));
    int*   sorted = (int*)  alloc((size_t)E_TOT * sizeof(int));

    // --- one memset for cnt+cur, then fused prep (cvt + count + 3 transposes)
    hipMemsetAsync(cntcur, 0, (size_t)2 * NNODES * sizeof(int), stream);
    prep_kernel<<<PREP_BLK, 256, 0, stream>>>(x, xh, ei, cnt,
                                              W1, W1t, W2, W2t, Wp, Wpt);
    scan_kernel<<<1, 1024, 0, stream>>>(cnt, indptr);
    scatter_kernel<<<(E_TOT + 255) / 256, 256, 0, stream>>>(ei, indptr, cur, sorted);

    dim3 g8(HC / 256, MPAD / 320);   // 8 x 32 = 256 blocks = one full round

    // Layer 1: H1 = x @ W1 (8-phase 320x256 fp16 MFMA)
    gemm8p_kernel<<<g8, 512, 0, stream>>>(xh, W1t, Hbuf, NNODES, IN_DIM, HC);
    attn_kernel<<<NNODES, 256, 0, stream>>>(Hbuf, a_src1, a_dst1, as1, ad1);
    agg_kernel<0><<<MPAD, 256, 0, stream>>>(Hbuf, as1, ad1, b1, indptr, sorted, ei, A2);

    // Layer 2: H2 = elu_agg @ W2 (8-phase 320x256 fp16 MFMA)
    gemm8p_kernel<<<g8, 512, 0, stream>>>(A2, W2t, Hbuf, NNODES, HC, HC);
    attn_kernel<<<NNODES, 256, 0, stream>>>(Hbuf, a_src2, a_dst2, as2, ad2);
    agg_kernel<1><<<MPAD, 256, 0, stream>>>(Hbuf, as2, ad2, b2, indptr, sorted, ei, out2h);

    // Projection + ReLU (128^2 fp16 MFMA, bias+relu fp32 epilogue)
    dim3 gProj(HID / 128, MPAD / 128);   // 2 x 80
    mfma_gemm_kernel<1><<<gProj, 256, 0, stream>>>(out2h, Wpt, out, bp,
                                                   NNODES, HID, HID, 0);
}

// Round 3
// 406.287 us; speedup vs baseline: 1.1850x; 1.0165x over previous
//
#include <hip/hip_runtime.h>
#include <cstdint>
#include <cstddef>

#define IN_DIM  768
#define NNODES  10000
#define MPAD    10240        // 32 * 320 (gemm8p) and 80 * 128 (proj GEMM)
#define NEDGES  80000
#define E_TOT   90000        // edges + self loops
#define HEADS   8
#define HID     256
#define HC      2048         // HEADS*HID
#define NEG_SLOPE 0.2f

// prep_kernel block ranges (256 threads each)
#define CVT_BLK  ((MPAD * IN_DIM / 4) / 256)          // 7680
#define CNT_BLK  ((E_TOT + 255) / 256)                // 352
#define T1_BLK   ((HC / 32) * (IN_DIM / 32))          // 1536
#define T2_BLK   ((HC / 32) * (HC / 32))              // 4096
#define TP_BLK   ((HID / 32) * (HID / 32))            // 64
#define PREP_BLK (CVT_BLK + CNT_BLK + T1_BLK + T2_BLK + TP_BLK)

typedef _Float16 __attribute__((ext_vector_type(8))) f16x8;
typedef float    __attribute__((ext_vector_type(4))) f32x4;

// ---------------------------------------------------------------------------
// edge helpers: edge ids [0,NEDGES) are real edges, [NEDGES,E_TOT) self loops
// ---------------------------------------------------------------------------
__device__ __forceinline__ int edge_src(const int* __restrict__ ei, int e) {
    return (e < NEDGES) ? ei[e] : (e - NEDGES);
}
__device__ __forceinline__ int edge_dst(const int* __restrict__ ei, int e) {
    return (e < NEDGES) ? ei[NEDGES + e] : (e - NEDGES);
}

// ---------------------------------------------------------------------------
// fused preprocessing (R9-proven): cvt + edge count + 3 weight transposes
// ---------------------------------------------------------------------------
__device__ __forceinline__ void tcvt_body(
    const float* __restrict__ W, _Float16* __restrict__ T,
    int K, int N, int bx, int by, int t)
{
    __shared__ float tile[32][33];
    int tx = t & 31, ty = t >> 5;   // 32 x 8
#pragma unroll
    for (int q = 0; q < 4; q++)
        tile[ty + q * 8][tx] = W[(size_t)(by * 32 + ty + q * 8) * N + bx * 32 + tx];
    __syncthreads();
#pragma unroll
    for (int q = 0; q < 4; q++) {
        float v = tile[tx][ty + q * 8];
        T[(size_t)(bx * 32 + ty + q * 8) * K + by * 32 + tx] = (_Float16)v;
    }
}

__global__ __launch_bounds__(256) void prep_kernel(
    const float* __restrict__ x, _Float16* __restrict__ xh,
    const int* __restrict__ ei, int* __restrict__ cnt,
    const float* __restrict__ W1, _Float16* __restrict__ W1t,
    const float* __restrict__ W2, _Float16* __restrict__ W2t,
    const float* __restrict__ Wp, _Float16* __restrict__ Wpt)
{
    int b = blockIdx.x;
    int t = threadIdx.x;
    if (b < CVT_BLK) {
        int i = b * 256 + t;
        size_t e = (size_t)i * 4;
        int r = (int)(e / IN_DIM);
        float4 v = (r < NNODES) ? *(const float4*)(x + e)
                                : make_float4(0.f, 0.f, 0.f, 0.f);
        _Float16 h4[4] = {(_Float16)v.x, (_Float16)v.y, (_Float16)v.z, (_Float16)v.w};
        *(ushort4*)(xh + e) = *(ushort4*)h4;
    } else if (b < CVT_BLK + CNT_BLK) {
        int e = (b - CVT_BLK) * 256 + t;
        if (e < E_TOT) atomicAdd(&cnt[edge_dst(ei, e)], 1);
    } else if (b < CVT_BLK + CNT_BLK + T1_BLK) {
        int idx = b - (CVT_BLK + CNT_BLK);
        tcvt_body(W1, W1t, IN_DIM, HC, idx % (HC / 32), idx / (HC / 32), t);
    } else if (b < CVT_BLK + CNT_BLK + T1_BLK + T2_BLK) {
        int idx = b - (CVT_BLK + CNT_BLK + T1_BLK);
        tcvt_body(W2, W2t, HC, HC, idx % (HC / 32), idx / (HC / 32), t);
    } else {
        int idx = b - (CVT_BLK + CNT_BLK + T1_BLK + T2_BLK);
        tcvt_body(Wp, Wpt, HID, HID, idx % (HID / 32), idx / (HID / 32), t);
    }
}

// ---------------------------------------------------------------------------
// CSR: scan + scatter (count fused into prep_kernel)
// ---------------------------------------------------------------------------
__global__ void scan_kernel(const int* __restrict__ cnt, int* __restrict__ indptr) {
    __shared__ int sums[1024];
    const int CH = 10;
    int t = threadIdx.x;
    int base = t * CH;
    int s = 0;
#pragma unroll
    for (int i = 0; i < CH; i++) { int idx = base + i; if (idx < NNODES) s += cnt[idx]; }
    sums[t] = s;
    __syncthreads();
    for (int off = 1; off < 1024; off <<= 1) {
        int v = (t >= off) ? sums[t - off] : 0;
        __syncthreads();
        sums[t] += v;
        __syncthreads();
    }
    int run = (t == 0) ? 0 : sums[t - 1];
#pragma unroll
    for (int i = 0; i < CH; i++) {
        int idx = base + i;
        if (idx < NNODES) { indptr[idx] = run; run += cnt[idx]; }
    }
    if (t == 0) indptr[NNODES] = E_TOT;
}

__global__ void scatter_kernel(const int* __restrict__ ei, const int* __restrict__ indptr,
                               int* __restrict__ cur, int* __restrict__ sorted) {
    int e = blockIdx.x * 256 + threadIdx.x;
    if (e < E_TOT) {
        int d = edge_dst(ei, e);
        int pos = atomicAdd(&cur[d], 1);
        sorted[indptr[d] + pos] = e;
    }
}

// ---------------------------------------------------------------------------
// 8-phase 320x256 fp16 MFMA GEMM, round-3 revision:
//   C[M,Nn] = A[Mpad,K] @ B[Nn,K]^T,  fp16 out, guard m < M.
// Grid 8 x 32 = 256 blocks = one full chip round (tail-free, round-2 proven).
// BK=64, 512 thr = 8 waves (2M x 4N), per-wave output 160x64, LDS 144 KiB.
//
// Round-3 changes (target: MfmaUtil 39 -> ~55):
//  1. GRAY-CODE quadrant order (0,0)->(0,1)->(1,1)->(1,0) with operand
//     REUSE: each phase reloads either fa or fb, never both. LDS reads
//     drop 56 -> 32 per wave per K-tile (-43% LDS traffic).
//  2. WAIT-AT-PHASE-START: vmcnt(N); barrier; ds_read; stage; lgkmcnt(0);
//     MFMA.  The landing guarantee now PRECEDES the reads (round-2 had it
//     after - formally racy), and the second barrier per phase is dropped:
//     the next phase's opening barrier is the write-after-read fence (a
//     wave passes barrier p+1 only after all waves completed lgkmcnt(0)
//     reads of phase p).  Barriers 8 -> 4 per K-tile.
//  3. Exact vmcnt re-derived for stage groups {A012 | B01 | B23 | A34}:
//     steady state p1=vmcnt(4) p2=vmcnt(5) p3=vmcnt(5) p4=none; every
//     waited load was issued >= 2 full phases earlier (> HBM latency).
//     Final tile: 4/2/0/none.
// T2 swizzle unchanged: 16B slot s of row r holds k-chunk (s ^ (r&7)),
// pre-swizzled global source + swizzled ds_read (rule #21).
// Requires K%64==0, K/64>=2, Nn%256==0, Mpad%320==0, nwg%8==0.
// ---------------------------------------------------------------------------
__global__ __launch_bounds__(512, 2) void gemm8p_kernel(
    const _Float16* __restrict__ A, const _Float16* __restrict__ B,
    _Float16* __restrict__ C, int M, int K, int Nn)
{
    __shared__ __align__(16) _Float16 lds[2][36864];   // 2 x (20480 A + 16384 B) = 144 KiB

    const int t = threadIdx.x;
    const int w = t >> 6, lane = t & 63;
    const int fr = lane & 15, q4 = lane >> 4;
    const int wr = w >> 2, wc = w & 3;        // 2 x 4 wave grid

    // bijective XCD chunk swizzle (nwg == 256, %8 == 0)
    const int nwgx = gridDim.x;
    int wg = blockIdx.y * nwgx + blockIdx.x;
    const int cpx = (nwgx * gridDim.y) >> 3;
    wg = (wg & 7) * cpx + (wg >> 3);
    const int row0 = (wg / nwgx) * 320;
    const int col0 = (wg % nwgx) * 256;

    // staging: load q covers rows [q*64, q*64+64), thread t -> row q*64 + (t>>3),
    // 16B slot t&7; swizzled global column = ((t&7) ^ (row&7)) * 8 elements.
    const int rowt = t >> 3;
    const int scol = ((t & 7) ^ (rowt & 7)) << 3;
    const _Float16* baseA = A + (size_t)(row0 + rowt) * K + scol;
    const _Float16* baseB = B + (size_t)(col0 + rowt) * K + scol;
    const int dstw = w * 512;                 // wave-uniform elem offset in a 4096-el load block

    auto stageA = [&](int q, int kel, int bb) {
        __builtin_amdgcn_global_load_lds(
            (const __attribute__((address_space(1))) void*)(baseA + (size_t)q * 64 * K + kel),
            (__attribute__((address_space(3))) void*)&lds[bb][q * 4096 + dstw], 16, 0, 0);
    };
    auto stageB = [&](int q, int kel, int bb) {
        __builtin_amdgcn_global_load_lds(
            (const __attribute__((address_space(1))) void*)(baseB + (size_t)q * 64 * K + kel),
            (__attribute__((address_space(3))) void*)&lds[bb][20480 + q * 4096 + dstw], 16, 0, 0);
    };

    f32x4 acc[2][2][5][2];
#pragma unroll
    for (int qm = 0; qm < 2; qm++)
#pragma unroll
        for (int qn = 0; qn < 2; qn++)
#pragma unroll
            for (int mi = 0; mi < 5; mi++)
#pragma unroll
                for (int ni = 0; ni < 2; ni++)
                    acc[qm][qn][mi][ni] = {0.f, 0.f, 0.f, 0.f};

    // persistent operand fragments (Gray-code reuse across phases)
    f16x8 fa[5][2], fb[2][2];

#define LOADA(BB, QM)                                                           \
    {                                                                           \
        _Pragma("unroll")                                                       \
        for (int mi = 0; mi < 5; mi++) {                                        \
            _Pragma("unroll")                                                   \
            for (int ks = 0; ks < 2; ks++) {                                    \
                int lr = wr * 80 + mi * 16 + fr;                                \
                int sl = ((ks << 2) | q4) ^ (fr & 7);                           \
                fa[mi][ks] = *(const f16x8*)&lds[BB][(QM) * 10240 + (lr << 6) + (sl << 3)]; \
            }                                                                   \
        }                                                                       \
    }
#define LOADB(BB, QN)                                                           \
    {                                                                           \
        _Pragma("unroll")                                                       \
        for (int ni = 0; ni < 2; ni++) {                                        \
            _Pragma("unroll")                                                   \
            for (int ks = 0; ks < 2; ks++) {                                    \
                int lr = wc * 32 + ni * 16 + fr;                                \
                int sl = ((ks << 2) | q4) ^ (fr & 7);                           \
                fb[ni][ks] = *(const f16x8*)&lds[BB][20480 + (QN) * 8192 + (lr << 6) + (sl << 3)]; \
            }                                                                   \
        }                                                                       \
    }

// one phase: WAIT (landing guarantee for this phase's reads) -> barrier ->
// ds_read (LOAD_STMT) -> issue next-tile stages -> lgkmcnt(0) -> MFMA.
// Single barrier per phase: the next phase's opening barrier fences WAR.
#define PHASE(QM, QN, LOAD_STMT, STAGE_STMT, WAIT_STMT)                         \
    do {                                                                        \
        WAIT_STMT;                                                              \
        __builtin_amdgcn_s_barrier();                                           \
        LOAD_STMT;                                                              \
        STAGE_STMT;                                                             \
        asm volatile("s_waitcnt lgkmcnt(0)" ::: "memory");                      \
        __builtin_amdgcn_sched_barrier(0);                                      \
        __builtin_amdgcn_s_setprio(1);                                          \
        _Pragma("unroll")                                                       \
        for (int ks = 0; ks < 2; ks++) {                                        \
            _Pragma("unroll")                                                   \
            for (int mi = 0; mi < 5; mi++) {                                    \
                _Pragma("unroll")                                               \
                for (int ni = 0; ni < 2; ni++)                                  \
                    acc[QM][QN][mi][ni] = __builtin_amdgcn_mfma_f32_16x16x32_f16(\
                        fa[mi][ks], fb[ni][ks], acc[QM][QN][mi][ni], 0, 0, 0);  \
            }                                                                   \
        }                                                                       \
        __builtin_amdgcn_s_setprio(0);                                          \
        __builtin_amdgcn_sched_barrier(0);                                      \
    } while (0)

#define VM(N) asm volatile("s_waitcnt vmcnt(" #N ")" ::: "memory")

    // prologue: stage tile 0 in wait-group order {A012, B01, B23, A34}
    stageA(0, 0, 0); stageA(1, 0, 0); stageA(2, 0, 0);
    stageB(0, 0, 0); stageB(1, 0, 0);
    stageB(2, 0, 0); stageB(3, 0, 0);
    stageA(3, 0, 0); stageA(4, 0, 0);

    const int nT = K >> 6;
    int t0 = 0;
    for (; t0 < nT - 1; ++t0) {
        int bb = t0 & 1;
        int bn = bb ^ 1;
        int k1 = (t0 + 1) << 6;
        PHASE(0, 0, { LOADA(bb, 0); LOADB(bb, 0); },
              { stageA(0, k1, bn); stageA(1, k1, bn); stageA(2, k1, bn); },
              VM(4));
        PHASE(0, 1, { LOADB(bb, 1); },
              { stageB(0, k1, bn); stageB(1, k1, bn); },
              VM(5));
        PHASE(1, 1, { LOADA(bb, 1); },
              { stageB(2, k1, bn); stageB(3, k1, bn); },
              VM(5));
        PHASE(1, 0, { LOADB(bb, 0); },
              { stageA(3, k1, bn); stageA(4, k1, bn); },
              ((void)0));
    }
    {   // final tile: no prefetch; exact residual drains
        int bb = t0 & 1;
        PHASE(0, 0, { LOADA(bb, 0); LOADB(bb, 0); }, ((void)0), VM(4));
        PHASE(0, 1, { LOADB(bb, 1); },               ((void)0), VM(2));
        PHASE(1, 1, { LOADA(bb, 1); },               ((void)0), VM(0));
        PHASE(1, 0, { LOADB(bb, 0); },               ((void)0), ((void)0));
    }
#undef PHASE
#undef LOADA
#undef LOADB
#undef VM

    // C/D layout (measured m89/m91): col = lane&15, row = quad*4 + reg
#pragma unroll
    for (int qm = 0; qm < 2; qm++)
#pragma unroll
        for (int qn = 0; qn < 2; qn++)
#pragma unroll
            for (int mi = 0; mi < 5; mi++) {
                int mb = row0 + qm * 160 + wr * 80 + mi * 16 + q4 * 4;
#pragma unroll
                for (int ni = 0; ni < 2; ni++) {
                    int n = col0 + qn * 128 + wc * 32 + ni * 16 + fr;
#pragma unroll
                    for (int r = 0; r < 4; r++) {
                        int m = mb + r;
                        if (m < M) C[(size_t)m * Nn + n] = (_Float16)acc[qm][qn][mi][ni][r];
                    }
                }
            }
}

// ---------------------------------------------------------------------------
// fp16 MFMA GEMM (128x128, BK=32, dbuf) — kept for the small projection GEMM
// (Nn=256 is too narrow for the 8-phase kernel).  EPI=1: fp32 relu(C + bias).
// ---------------------------------------------------------------------------
template <int EPI>
__global__ __launch_bounds__(256) void mfma_gemm_kernel(
    const _Float16* __restrict__ A, const _Float16* __restrict__ B,
    void* __restrict__ Cout, const float* __restrict__ bias,
    int M, int K, int Nn, int swz)
{
    __shared__ __align__(16) _Float16 sA[2][128 * 32];   // 2 x 8 KB
    __shared__ __align__(16) _Float16 sB[2][128 * 32];   // 2 x 8 KB

    int t = threadIdx.x;
    int bx = blockIdx.x, by = blockIdx.y;
    if (swz) {                       // gridDim.x == 16 only
        int id = by * 16 + bx;
        int xcd = id & 7, slot = id >> 3;
        bx = 2 * xcd + (slot & 1);
        by = slot >> 1;
    }
    int row0 = by * 128;
    int col0 = bx * 128;

    int s0 = t, s1 = t + 256;
    int m0 = s0 >> 2, k0 = (s0 & 3) * 8;
    int m1 = s1 >> 2, k1 = (s1 & 3) * 8;
    const _Float16* a0 = A + (size_t)(row0 + m0) * K + k0;
    const _Float16* a1 = A + (size_t)(row0 + m1) * K + k1;
    const _Float16* b0 = B + (size_t)(col0 + m0) * K + k0;
    const _Float16* b1 = B + (size_t)(col0 + m1) * K + k1;

    int w = t >> 6, lane = t & 63;
    int wm = (w & 1) * 64, wn = (w >> 1) * 64;
    int fr = lane & 15, quad = lane >> 4;

    auto stage = [&](int kt, int bsel) {
        _Float16* dA0 = &sA[bsel][(w * 64) * 8];
        _Float16* dA1 = &sA[bsel][(w * 64 + 256) * 8];
        _Float16* dB0 = &sB[bsel][(w * 64) * 8];
        _Float16* dB1 = &sB[bsel][(w * 64 + 256) * 8];
        __builtin_amdgcn_global_load_lds(
            (const __attribute__((address_space(1))) void*)(a0 + kt),
            (__attribute__((address_space(3))) void*)dA0, 16, 0, 0);
        __builtin_amdgcn_global_load_lds(
            (const __attribute__((address_space(1))) void*)(a1 + kt),
            (__attribute__((address_space(3))) void*)dA1, 16, 0, 0);
        __builtin_amdgcn_global_load_lds(
            (const __attribute__((address_space(1))) void*)(b0 + kt),
            (__attribute__((address_space(3))) void*)dB0, 16, 0, 0);
        __builtin_amdgcn_global_load_lds(
            (const __attribute__((address_space(1))) void*)(b1 + kt),
            (__attribute__((address_space(3))) void*)dB1, 16, 0, 0);
    };

    f32x4 acc[4][4];
#pragma unroll
    for (int i = 0; i < 4; i++)
#pragma unroll
        for (int j = 0; j < 4; j++) acc[i][j] = {0.f, 0.f, 0.f, 0.f};

    const int nIt = K / 32;
    stage(0, 0);
    __syncthreads();

    for (int it = 0; it < nIt; ++it) {
        int cb = it & 1;
        if (it + 1 < nIt) stage((it + 1) * 32, cb ^ 1);

        f16x8 fa[4], fb[4];
#pragma unroll
        for (int i = 0; i < 4; i++) {
            fa[i] = *(const f16x8*)&sA[cb][(wm + i * 16 + fr) * 32 + quad * 8];
            fb[i] = *(const f16x8*)&sB[cb][(wn + i * 16 + fr) * 32 + quad * 8];
        }
#pragma unroll
        for (int i = 0; i < 4; i++)
#pragma unroll
            for (int j = 0; j < 4; j++)
                acc[i][j] = __builtin_amdgcn_mfma_f32_16x16x32_f16(fa[i], fb[j], acc[i][j], 0, 0, 0);

        if (it + 1 < nIt) __syncthreads();
    }

    if (EPI == 0) {
        _Float16* C = (_Float16*)Cout;
#pragma unroll
        for (int i = 0; i < 4; i++) {
            int mbase = row0 + wm + i * 16 + quad * 4;
#pragma unroll
            for (int j = 0; j < 4; j++) {
                int n = col0 + wn + j * 16 + fr;
#pragma unroll
                for (int r = 0; r < 4; r++) {
                    int m = mbase + r;
                    if (m < M) C[(size_t)m * Nn + n] = (_Float16)acc[i][j][r];
                }
            }
        }
    } else {
        float* C = (float*)Cout;
        float bv[4];
#pragma unroll
        for (int j = 0; j < 4; j++) bv[j] = bias[col0 + wn + j * 16 + fr];
#pragma unroll
        for (int i = 0; i < 4; i++) {
            int mbase = row0 + wm + i * 16 + quad * 4;
#pragma unroll
            for (int j = 0; j < 4; j++) {
                int n = col0 + wn + j * 16 + fr;
#pragma unroll
                for (int r = 0; r < 4; r++) {
                    int m = mbase + r;
                    if (m < M) C[(size_t)m * Nn + n] = fmaxf(acc[i][j][r] + bv[j], 0.f);
                }
            }
        }
    }
}

// ---------------------------------------------------------------------------
// per-node attention coefficients from fp16 H
// ---------------------------------------------------------------------------
__global__ __launch_bounds__(256) void attn_kernel(
    const _Float16* __restrict__ H, const float* __restrict__ a_src,
    const float* __restrict__ a_dst, float* __restrict__ as_out,
    float* __restrict__ ad_out)
{
    int n = blockIdx.x;
    int t = threadIdx.x;
    int h = t >> 5, l = t & 31;
    f16x8 hv = *(const f16x8*)&H[(size_t)n * HC + h * HID + l * 8];
    const float* asp = a_src + h * HID + l * 8;
    const float* adp = a_dst + h * HID + l * 8;
    float sa = 0.f, sd = 0.f;
#pragma unroll
    for (int q = 0; q < 8; q++) {
        float v = (float)hv[q];
        sa = fmaf(v, asp[q], sa);
        sd = fmaf(v, adp[q], sd);
    }
#pragma unroll
    for (int o = 16; o > 0; o >>= 1) {
        sa += __shfl_xor(sa, o, 32);
        sd += __shfl_xor(sd, o, 32);
    }
    if (l == 0) { as_out[n * HEADS + h] = sa; ad_out[n * HEADS + h] = sd; }
}

// ---------------------------------------------------------------------------
// per-dst-node gather aggregation with segment softmax.  (unchanged R10 body)
// ---------------------------------------------------------------------------
template <int MODE>
__global__ __launch_bounds__(256) void agg_kernel(
    const _Float16* __restrict__ H, const float* __restrict__ as_,
    const float* __restrict__ ad_, const float* __restrict__ bias,
    const int* __restrict__ indptr, const int* __restrict__ sorted,
    const int* __restrict__ ei, _Float16* __restrict__ outh)
{
    __shared__ float m8[HEADS], d8[HEADS], adl[HEADS];
    __shared__ int   srcl[64];
    __shared__ float al[64][HEADS];
    __shared__ float red[HC];          // MODE 1 cross-head reduction

    int n = blockIdx.x;
    int t = threadIdx.x;

    if (n >= NNODES) {                 // pad rows for the next MFMA GEMM
        if (MODE == 0) {
            _Float16 z8[8] = {};
            *(f16x8*)&outh[(size_t)n * HC + t * 8] = *(f16x8*)z8;
        } else {
            outh[(size_t)n * HID + t] = (_Float16)0.f;
        }
        return;
    }

    int start = indptr[n];
    int deg = indptr[n + 1] - start;

    if (t < HEADS) adl[t] = ad_[n * HEADS + t];
    __syncthreads();

    int h = t >> 5, l = t & 31;
    float adh = adl[h];

    float mx = -1e30f;
    for (int j = l; j < deg; j += 32) {
        int e = sorted[start + j];
        int s = edge_src(ei, e);
        float v = as_[s * HEADS + h] + adh;
        v = (v >= 0.f) ? v : NEG_SLOPE * v;
        mx = fmaxf(mx, v);
    }
#pragma unroll
    for (int o = 16; o > 0; o >>= 1) mx = fmaxf(mx, __shfl_xor(mx, o, 32));

    float sm = 0.f;
    for (int j = l; j < deg; j += 32) {
        int e = sorted[start + j];
        int s = edge_src(ei, e);
        float v = as_[s * HEADS + h] + adh;
        v = (v >= 0.f) ? v : NEG_SLOPE * v;
        sm += expf(v - mx);
    }
#pragma unroll
    for (int o = 16; o > 0; o >>= 1) sm += __shfl_xor(sm, o, 32);
    if (l == 0) { m8[h] = mx; d8[h] = sm; }

    int hh = t >> 5, c8 = (t & 31) * 8;
    const size_t hoff = (size_t)hh * HID + c8;
    float acc[8] = {};
    for (int base = 0; base < deg; base += 64) {
        int cntc = min(64, deg - base);
        __syncthreads();
        if (t < cntc) srcl[t] = edge_src(ei, sorted[start + base + t]);
        __syncthreads();
        {
            int j = t & 63, h0 = t >> 6;
            if (j < cntc) {
#pragma unroll
                for (int q = 0; q < 2; q++) {
                    int hx = h0 + q * 4;
                    float v = as_[srcl[j] * HEADS + hx] + adl[hx];
                    v = (v >= 0.f) ? v : NEG_SLOPE * v;
                    al[j][hx] = expf(v - m8[hx]) / (d8[hx] + 1e-16f);
                }
            }
        }
        __syncthreads();
        int jj = 0;
        for (; jj + 3 < cntc; jj += 4) {
            int sx0 = srcl[jj + 0], sx1 = srcl[jj + 1];
            int sx2 = srcl[jj + 2], sx3 = srcl[jj + 3];
            f16x8 h0v = *(const f16x8*)&H[(size_t)sx0 * HC + hoff];
            f16x8 h1v = *(const f16x8*)&H[(size_t)sx1 * HC + hoff];
            f16x8 h2v = *(const f16x8*)&H[(size_t)sx2 * HC + hoff];
            f16x8 h3v = *(const f16x8*)&H[(size_t)sx3 * HC + hoff];
            float a0 = al[jj + 0][hh], a1 = al[jj + 1][hh];
            float a2 = al[jj + 2][hh], a3 = al[jj + 3][hh];
#pragma unroll
            for (int q = 0; q < 8; q++) acc[q] = fmaf(a0, (float)h0v[q], acc[q]);
#pragma unroll
            for (int q = 0; q < 8; q++) acc[q] = fmaf(a1, (float)h1v[q], acc[q]);
#pragma unroll
            for (int q = 0; q < 8; q++) acc[q] = fmaf(a2, (float)h2v[q], acc[q]);
#pragma unroll
            for (int q = 0; q < 8; q++) acc[q] = fmaf(a3, (float)h3v[q], acc[q]);
        }
        for (; jj < cntc; jj++) {
            int s = srcl[jj];
            f16x8 hv = *(const f16x8*)&H[(size_t)s * HC + hoff];
            float a = al[jj][hh];
#pragma unroll
            for (int q = 0; q < 8; q++)
                acc[q] = fmaf(a, (float)hv[q], acc[q]);
        }
    }

    if (MODE == 0) {
        _Float16 o8[8];
#pragma unroll
        for (int q = 0; q < 8; q++) {
            float v = acc[q] + bias[hoff + q];
            v = (v > 0.f) ? v : expm1f(v);          // ELU (alpha=1)
            o8[q] = (_Float16)v;
        }
        *(f16x8*)&outh[(size_t)n * HC + hoff] = *(f16x8*)o8;
    } else {
#pragma unroll
        for (int q = 0; q < 8; q++) red[hoff + q] = acc[q];
        __syncthreads();
        float s = 0.f;
#pragma unroll
        for (int h2 = 0; h2 < HEADS; h2++) s += red[h2 * HID + t];
        outh[(size_t)n * HID + t] = (_Float16)(s * 0.125f + bias[t]);
    }
}

// ---------------------------------------------------------------------------
extern "C" void kernel_launch(void* const* d_in, const int* in_sizes, int n_in,
                              void* d_out, int out_size, void* d_ws, size_t ws_size,
                              hipStream_t stream)
{
    const float* x      = (const float*)d_in[0];
    const int*   ei     = (const int*)  d_in[1];
    const float* W1     = (const float*)d_in[2];
    const float* a_src1 = (const float*)d_in[3];
    const float* a_dst1 = (const float*)d_in[4];
    const float* b1     = (const float*)d_in[5];
    const float* W2     = (const float*)d_in[6];
    const float* a_src2 = (const float*)d_in[7];
    const float* a_dst2 = (const float*)d_in[8];
    const float* b2     = (const float*)d_in[9];
    const float* Wp     = (const float*)d_in[10];
    const float* bp     = (const float*)d_in[11];
    float* out = (float*)d_out;

    char* ws = (char*)d_ws;
    size_t off = 0;
    auto alloc = [&](size_t bytes) -> char* {
        char* p = ws + off;
        off += (bytes + 255) & ~(size_t)255;
        return p;
    };
    _Float16* Hbuf = (_Float16*)alloc((size_t)NNODES * HC * 2);          // 41 MB (H1, then H2)
    _Float16* A2   = (_Float16*)alloc((size_t)MPAD * HC * 2);            // 41.9 MB
    _Float16* W1t  = (_Float16*)alloc((size_t)HC * IN_DIM * 2);          // 3.1 MB
    _Float16* W2t  = (_Float16*)alloc((size_t)HC * HC * 2);              // 8.4 MB
    _Float16* Wpt  = (_Float16*)alloc((size_t)HID * HID * 2);            // 128 KB
    _Float16* xh   = (_Float16*)alloc((size_t)MPAD * IN_DIM * 2);        // 15.7 MB
    _Float16* out2h = (_Float16*)alloc((size_t)MPAD * HID * 2);          // 5.2 MB
    float* asad   = (float*)alloc((size_t)4 * NNODES * HEADS * sizeof(float));
    float* as1 = asad;
    float* ad1 = asad + (size_t)NNODES * HEADS;
    float* as2 = asad + (size_t)2 * NNODES * HEADS;
    float* ad2 = asad + (size_t)3 * NNODES * HEADS;
    int*   cntcur = (int*)alloc((size_t)2 * NNODES * sizeof(int));   // cnt | cur contiguous
    int*   cnt = cntcur;
    int*   cur = cntcur + NNODES;
    int*   indptr = (int*)  alloc((size_t)(NNODES + 1) * sizeof(int));
    int*   sorted = (int*)  alloc((size_t)E_TOT * sizeof(int));

    // --- one memset for cnt+cur, then fused prep (cvt + count + 3 transposes)
    hipMemsetAsync(cntcur, 0, (size_t)2 * NNODES * sizeof(int), stream);
    prep_kernel<<<PREP_BLK, 256, 0, stream>>>(x, xh, ei, cnt,
                                              W1, W1t, W2, W2t, Wp, Wpt);
    scan_kernel<<<1, 1024, 0, stream>>>(cnt, indptr);
    scatter_kernel<<<(E_TOT + 255) / 256, 256, 0, stream>>>(ei, indptr, cur, sorted);

    dim3 g8(HC / 256, MPAD / 320);   // 8 x 32 = 256 blocks = one full round

    // Layer 1: H1 = x @ W1 (8-phase 320x256 fp16 MFMA)
    gemm8p_kernel<<<g8, 512, 0, stream>>>(xh, W1t, Hbuf, NNODES, IN_DIM, HC);
    attn_kernel<<<NNODES, 256, 0, stream>>>(Hbuf, a_src1, a_dst1, as1, ad1);
    agg_kernel<0><<<MPAD, 256, 0, stream>>>(Hbuf, as1, ad1, b1, indptr, sorted, ei, A2);

    // Layer 2: H2 = elu_agg @ W2 (8-phase 320x256 fp16 MFMA)
    gemm8p_kernel<<<g8, 512, 0, stream>>>(A2, W2t, Hbuf, NNODES, HC, HC);
    attn_kernel<<<NNODES, 256, 0, stream>>>(Hbuf, a_src2, a_dst2, as2, ad2);
    agg_kernel<1><<<MPAD, 256, 0, stream>>>(Hbuf, as2, ad2, b2, indptr, sorted, ei, out2h);

    // Projection + ReLU (128^2 fp16 MFMA, bias+relu fp32 epilogue)
    dim3 gProj(HID / 128, MPAD / 128);   // 2 x 80
    mfma_gemm_kernel<1><<<gProj, 256, 0, stream>>>(out2h, Wpt, out, bp,
                                                   NNODES, HID, HID, 0);
}

// Round 4
// 393.391 us; speedup vs baseline: 1.2239x; 1.0328x over previous
//
#include <hip/hip_runtime.h>
#include <cstdint>
#include <cstddef>

#define IN_DIM  768
#define NNODES  10000
#define MPAD    10240        // 32 * 320 (gemm8p) and 80 * 128 (proj GEMM)
#define NEDGES  80000
#define E_TOT   90000        // edges + self loops
#define HEADS   8
#define HID     256
#define HC      2048         // HEADS*HID
#define NEG_SLOPE 0.2f

// prep_kernel block ranges (256 threads each)
#define CVT_BLK  ((MPAD * IN_DIM / 4) / 256)          // 7680
#define CNT_BLK  ((E_TOT + 255) / 256)                // 352
#define T1_BLK   ((HC / 32) * (IN_DIM / 32))          // 1536
#define T2_BLK   ((HC / 32) * (HC / 32))              // 4096
#define TP_BLK   ((HID / 32) * (HID / 32))            // 64
#define PREP_BLK (CVT_BLK + CNT_BLK + T1_BLK + T2_BLK + TP_BLK)

typedef _Float16 __attribute__((ext_vector_type(8))) f16x8;
typedef float    __attribute__((ext_vector_type(4))) f32x4;

// ---------------------------------------------------------------------------
// edge helpers: edge ids [0,NEDGES) are real edges, [NEDGES,E_TOT) self loops
// ---------------------------------------------------------------------------
__device__ __forceinline__ int edge_src(const int* __restrict__ ei, int e) {
    return (e < NEDGES) ? ei[e] : (e - NEDGES);
}
__device__ __forceinline__ int edge_dst(const int* __restrict__ ei, int e) {
    return (e < NEDGES) ? ei[NEDGES + e] : (e - NEDGES);
}

// ---------------------------------------------------------------------------
// fused preprocessing (R9-proven): cvt + edge count + 3 weight transposes
// ---------------------------------------------------------------------------
__device__ __forceinline__ void tcvt_body(
    const float* __restrict__ W, _Float16* __restrict__ T,
    int K, int N, int bx, int by, int t)
{
    __shared__ float tile[32][33];
    int tx = t & 31, ty = t >> 5;   // 32 x 8
#pragma unroll
    for (int q = 0; q < 4; q++)
        tile[ty + q * 8][tx] = W[(size_t)(by * 32 + ty + q * 8) * N + bx * 32 + tx];
    __syncthreads();
#pragma unroll
    for (int q = 0; q < 4; q++) {
        float v = tile[tx][ty + q * 8];
        T[(size_t)(bx * 32 + ty + q * 8) * K + by * 32 + tx] = (_Float16)v;
    }
}

__global__ __launch_bounds__(256) void prep_kernel(
    const float* __restrict__ x, _Float16* __restrict__ xh,
    const int* __restrict__ ei, int* __restrict__ cnt,
    const float* __restrict__ W1, _Float16* __restrict__ W1t,
    const float* __restrict__ W2, _Float16* __restrict__ W2t,
    const float* __restrict__ Wp, _Float16* __restrict__ Wpt)
{
    int b = blockIdx.x;
    int t = threadIdx.x;
    if (b < CVT_BLK) {
        int i = b * 256 + t;
        size_t e = (size_t)i * 4;
        int r = (int)(e / IN_DIM);
        float4 v = (r < NNODES) ? *(const float4*)(x + e)
                                : make_float4(0.f, 0.f, 0.f, 0.f);
        _Float16 h4[4] = {(_Float16)v.x, (_Float16)v.y, (_Float16)v.z, (_Float16)v.w};
        *(ushort4*)(xh + e) = *(ushort4*)h4;
    } else if (b < CVT_BLK + CNT_BLK) {
        int e = (b - CVT_BLK) * 256 + t;
        if (e < E_TOT) atomicAdd(&cnt[edge_dst(ei, e)], 1);
    } else if (b < CVT_BLK + CNT_BLK + T1_BLK) {
        int idx = b - (CVT_BLK + CNT_BLK);
        tcvt_body(W1, W1t, IN_DIM, HC, idx % (HC / 32), idx / (HC / 32), t);
    } else if (b < CVT_BLK + CNT_BLK + T1_BLK + T2_BLK) {
        int idx = b - (CVT_BLK + CNT_BLK + T1_BLK);
        tcvt_body(W2, W2t, HC, HC, idx % (HC / 32), idx / (HC / 32), t);
    } else {
        int idx = b - (CVT_BLK + CNT_BLK + T1_BLK + T2_BLK);
        tcvt_body(Wp, Wpt, HID, HID, idx % (HID / 32), idx / (HID / 32), t);
    }
}

// ---------------------------------------------------------------------------
// CSR: scan + scatter (count fused into prep_kernel)
// ---------------------------------------------------------------------------
__global__ void scan_kernel(const int* __restrict__ cnt, int* __restrict__ indptr) {
    __shared__ int sums[1024];
    const int CH = 10;
    int t = threadIdx.x;
    int base = t * CH;
    int s = 0;
#pragma unroll
    for (int i = 0; i < CH; i++) { int idx = base + i; if (idx < NNODES) s += cnt[idx]; }
    sums[t] = s;
    __syncthreads();
    for (int off = 1; off < 1024; off <<= 1) {
        int v = (t >= off) ? sums[t - off] : 0;
        __syncthreads();
        sums[t] += v;
        __syncthreads();
    }
    int run = (t == 0) ? 0 : sums[t - 1];
#pragma unroll
    for (int i = 0; i < CH; i++) {
        int idx = base + i;
        if (idx < NNODES) { indptr[idx] = run; run += cnt[idx]; }
    }
    if (t == 0) indptr[NNODES] = E_TOT;
}

__global__ void scatter_kernel(const int* __restrict__ ei, const int* __restrict__ indptr,
                               int* __restrict__ cur, int* __restrict__ sorted) {
    int e = blockIdx.x * 256 + threadIdx.x;
    if (e < E_TOT) {
        int d = edge_dst(ei, e);
        int pos = atomicAdd(&cur[d], 1);
        sorted[indptr[d] + pos] = e;
    }
}

// ---------------------------------------------------------------------------
// 8-phase 320x256 fp16 MFMA GEMM (round-3 proven: Gray-code quadrants,
// wait-at-phase-start, 4 barriers/K-tile, exact vmcnt).
//   C[M,Nn] = A[Mpad,K] @ B[Nn,K]^T,  fp16 out, guard m < M.
// Grid 8 x 32 = 256 blocks = one full chip round.
// Requires K%64==0, K/64>=2, Nn%256==0, Mpad%320==0, nwg%8==0.
// ---------------------------------------------------------------------------
__global__ __launch_bounds__(512, 2) void gemm8p_kernel(
    const _Float16* __restrict__ A, const _Float16* __restrict__ B,
    _Float16* __restrict__ C, int M, int K, int Nn)
{
    __shared__ __align__(16) _Float16 lds[2][36864];   // 2 x (20480 A + 16384 B) = 144 KiB

    const int t = threadIdx.x;
    const int w = t >> 6, lane = t & 63;
    const int fr = lane & 15, q4 = lane >> 4;
    const int wr = w >> 2, wc = w & 3;        // 2 x 4 wave grid

    // bijective XCD chunk swizzle (nwg == 256, %8 == 0)
    const int nwgx = gridDim.x;
    int wg = blockIdx.y * nwgx + blockIdx.x;
    const int cpx = (nwgx * gridDim.y) >> 3;
    wg = (wg & 7) * cpx + (wg >> 3);
    const int row0 = (wg / nwgx) * 320;
    const int col0 = (wg % nwgx) * 256;

    // staging: load q covers rows [q*64, q*64+64), thread t -> row q*64 + (t>>3),
    // 16B slot t&7; swizzled global column = ((t&7) ^ (row&7)) * 8 elements.
    const int rowt = t >> 3;
    const int scol = ((t & 7) ^ (rowt & 7)) << 3;
    const _Float16* baseA = A + (size_t)(row0 + rowt) * K + scol;
    const _Float16* baseB = B + (size_t)(col0 + rowt) * K + scol;
    const int dstw = w * 512;                 // wave-uniform elem offset in a 4096-el load block

    auto stageA = [&](int q, int kel, int bb) {
        __builtin_amdgcn_global_load_lds(
            (const __attribute__((address_space(1))) void*)(baseA + (size_t)q * 64 * K + kel),
            (__attribute__((address_space(3))) void*)&lds[bb][q * 4096 + dstw], 16, 0, 0);
    };
    auto stageB = [&](int q, int kel, int bb) {
        __builtin_amdgcn_global_load_lds(
            (const __attribute__((address_space(1))) void*)(baseB + (size_t)q * 64 * K + kel),
            (__attribute__((address_space(3))) void*)&lds[bb][20480 + q * 4096 + dstw], 16, 0, 0);
    };

    f32x4 acc[2][2][5][2];
#pragma unroll
    for (int qm = 0; qm < 2; qm++)
#pragma unroll
        for (int qn = 0; qn < 2; qn++)
#pragma unroll
            for (int mi = 0; mi < 5; mi++)
#pragma unroll
                for (int ni = 0; ni < 2; ni++)
                    acc[qm][qn][mi][ni] = {0.f, 0.f, 0.f, 0.f};

    // persistent operand fragments (Gray-code reuse across phases)
    f16x8 fa[5][2], fb[2][2];

#define LOADA(BB, QM)                                                           \
    {                                                                           \
        _Pragma("unroll")                                                       \
        for (int mi = 0; mi < 5; mi++) {                                        \
            _Pragma("unroll")                                                   \
            for (int ks = 0; ks < 2; ks++) {                                    \
                int lr = wr * 80 + mi * 16 + fr;                                \
                int sl = ((ks << 2) | q4) ^ (fr & 7);                           \
                fa[mi][ks] = *(const f16x8*)&lds[BB][(QM) * 10240 + (lr << 6) + (sl << 3)]; \
            }                                                                   \
        }                                                                       \
    }
#define LOADB(BB, QN)                                                           \
    {                                                                           \
        _Pragma("unroll")                                                       \
        for (int ni = 0; ni < 2; ni++) {                                        \
            _Pragma("unroll")                                                   \
            for (int ks = 0; ks < 2; ks++) {                                    \
                int lr = wc * 32 + ni * 16 + fr;                                \
                int sl = ((ks << 2) | q4) ^ (fr & 7);                           \
                fb[ni][ks] = *(const f16x8*)&lds[BB][20480 + (QN) * 8192 + (lr << 6) + (sl << 3)]; \
            }                                                                   \
        }                                                                       \
    }

// one phase: WAIT (landing guarantee for this phase's reads) -> barrier ->
// ds_read (LOAD_STMT) -> issue next-tile stages -> lgkmcnt(0) -> MFMA.
// Single barrier per phase: the next phase's opening barrier fences WAR.
#define PHASE(QM, QN, LOAD_STMT, STAGE_STMT, WAIT_STMT)                         \
    do {                                                                        \
        WAIT_STMT;                                                              \
        __builtin_amdgcn_s_barrier();                                           \
        LOAD_STMT;                                                              \
        STAGE_STMT;                                                             \
        asm volatile("s_waitcnt lgkmcnt(0)" ::: "memory");                      \
        __builtin_amdgcn_sched_barrier(0);                                      \
        __builtin_amdgcn_s_setprio(1);                                          \
        _Pragma("unroll")                                                       \
        for (int ks = 0; ks < 2; ks++) {                                        \
            _Pragma("unroll")                                                   \
            for (int mi = 0; mi < 5; mi++) {                                    \
                _Pragma("unroll")                                               \
                for (int ni = 0; ni < 2; ni++)                                  \
                    acc[QM][QN][mi][ni] = __builtin_amdgcn_mfma_f32_16x16x32_f16(\
                        fa[mi][ks], fb[ni][ks], acc[QM][QN][mi][ni], 0, 0, 0);  \
            }                                                                   \
        }                                                                       \
        __builtin_amdgcn_s_setprio(0);                                          \
        __builtin_amdgcn_sched_barrier(0);                                      \
    } while (0)

#define VM(N) asm volatile("s_waitcnt vmcnt(" #N ")" ::: "memory")

    // prologue: stage tile 0 in wait-group order {A012, B01, B23, A34}
    stageA(0, 0, 0); stageA(1, 0, 0); stageA(2, 0, 0);
    stageB(0, 0, 0); stageB(1, 0, 0);
    stageB(2, 0, 0); stageB(3, 0, 0);
    stageA(3, 0, 0); stageA(4, 0, 0);

    const int nT = K >> 6;
    int t0 = 0;
    for (; t0 < nT - 1; ++t0) {
        int bb = t0 & 1;
        int bn = bb ^ 1;
        int k1 = (t0 + 1) << 6;
        PHASE(0, 0, { LOADA(bb, 0); LOADB(bb, 0); },
              { stageA(0, k1, bn); stageA(1, k1, bn); stageA(2, k1, bn); },
              VM(4));
        PHASE(0, 1, { LOADB(bb, 1); },
              { stageB(0, k1, bn); stageB(1, k1, bn); },
              VM(5));
        PHASE(1, 1, { LOADA(bb, 1); },
              { stageB(2, k1, bn); stageB(3, k1, bn); },
              VM(5));
        PHASE(1, 0, { LOADB(bb, 0); },
              { stageA(3, k1, bn); stageA(4, k1, bn); },
              ((void)0));
    }
    {   // final tile: no prefetch; exact residual drains
        int bb = t0 & 1;
        PHASE(0, 0, { LOADA(bb, 0); LOADB(bb, 0); }, ((void)0), VM(4));
        PHASE(0, 1, { LOADB(bb, 1); },               ((void)0), VM(2));
        PHASE(1, 1, { LOADA(bb, 1); },               ((void)0), VM(0));
        PHASE(1, 0, { LOADB(bb, 0); },               ((void)0), ((void)0));
    }
#undef PHASE
#undef LOADA
#undef LOADB
#undef VM

    // C/D layout (measured m89/m91): col = lane&15, row = quad*4 + reg
#pragma unroll
    for (int qm = 0; qm < 2; qm++)
#pragma unroll
        for (int qn = 0; qn < 2; qn++)
#pragma unroll
            for (int mi = 0; mi < 5; mi++) {
                int mb = row0 + qm * 160 + wr * 80 + mi * 16 + q4 * 4;
#pragma unroll
                for (int ni = 0; ni < 2; ni++) {
                    int n = col0 + qn * 128 + wc * 32 + ni * 16 + fr;
#pragma unroll
                    for (int r = 0; r < 4; r++) {
                        int m = mb + r;
                        if (m < M) C[(size_t)m * Nn + n] = (_Float16)acc[qm][qn][mi][ni][r];
                    }
                }
            }
}

// ---------------------------------------------------------------------------
// fp16 MFMA GEMM (128x128, BK=32, dbuf) — kept for the small projection GEMM
// (Nn=256 is too narrow for the 8-phase kernel).  EPI=1: fp32 relu(C + bias).
// ---------------------------------------------------------------------------
template <int EPI>
__global__ __launch_bounds__(256) void mfma_gemm_kernel(
    const _Float16* __restrict__ A, const _Float16* __restrict__ B,
    void* __restrict__ Cout, const float* __restrict__ bias,
    int M, int K, int Nn, int swz)
{
    __shared__ __align__(16) _Float16 sA[2][128 * 32];   // 2 x 8 KB
    __shared__ __align__(16) _Float16 sB[2][128 * 32];   // 2 x 8 KB

    int t = threadIdx.x;
    int bx = blockIdx.x, by = blockIdx.y;
    if (swz) {                       // gridDim.x == 16 only
        int id = by * 16 + bx;
        int xcd = id & 7, slot = id >> 3;
        bx = 2 * xcd + (slot & 1);
        by = slot >> 1;
    }
    int row0 = by * 128;
    int col0 = bx * 128;

    int s0 = t, s1 = t + 256;
    int m0 = s0 >> 2, k0 = (s0 & 3) * 8;
    int m1 = s1 >> 2, k1 = (s1 & 3) * 8;
    const _Float16* a0 = A + (size_t)(row0 + m0) * K + k0;
    const _Float16* a1 = A + (size_t)(row0 + m1) * K + k1;
    const _Float16* b0 = B + (size_t)(col0 + m0) * K + k0;
    const _Float16* b1 = B + (size_t)(col0 + m1) * K + k1;

    int w = t >> 6, lane = t & 63;
    int wm = (w & 1) * 64, wn = (w >> 1) * 64;
    int fr = lane & 15, quad = lane >> 4;

    auto stage = [&](int kt, int bsel) {
        _Float16* dA0 = &sA[bsel][(w * 64) * 8];
        _Float16* dA1 = &sA[bsel][(w * 64 + 256) * 8];
        _Float16* dB0 = &sB[bsel][(w * 64) * 8];
        _Float16* dB1 = &sB[bsel][(w * 64 + 256) * 8];
        __builtin_amdgcn_global_load_lds(
            (const __attribute__((address_space(1))) void*)(a0 + kt),
            (__attribute__((address_space(3))) void*)dA0, 16, 0, 0);
        __builtin_amdgcn_global_load_lds(
            (const __attribute__((address_space(1))) void*)(a1 + kt),
            (__attribute__((address_space(3))) void*)dA1, 16, 0, 0);
        __builtin_amdgcn_global_load_lds(
            (const __attribute__((address_space(1))) void*)(b0 + kt),
            (__attribute__((address_space(3))) void*)dB0, 16, 0, 0);
        __builtin_amdgcn_global_load_lds(
            (const __attribute__((address_space(1))) void*)(b1 + kt),
            (__attribute__((address_space(3))) void*)dB1, 16, 0, 0);
    };

    f32x4 acc[4][4];
#pragma unroll
    for (int i = 0; i < 4; i++)
#pragma unroll
        for (int j = 0; j < 4; j++) acc[i][j] = {0.f, 0.f, 0.f, 0.f};

    const int nIt = K / 32;
    stage(0, 0);
    __syncthreads();

    for (int it = 0; it < nIt; ++it) {
        int cb = it & 1;
        if (it + 1 < nIt) stage((it + 1) * 32, cb ^ 1);

        f16x8 fa[4], fb[4];
#pragma unroll
        for (int i = 0; i < 4; i++) {
            fa[i] = *(const f16x8*)&sA[cb][(wm + i * 16 + fr) * 32 + quad * 8];
            fb[i] = *(const f16x8*)&sB[cb][(wn + i * 16 + fr) * 32 + quad * 8];
        }
#pragma unroll
        for (int i = 0; i < 4; i++)
#pragma unroll
            for (int j = 0; j < 4; j++)
                acc[i][j] = __builtin_amdgcn_mfma_f32_16x16x32_f16(fa[i], fb[j], acc[i][j], 0, 0, 0);

        if (it + 1 < nIt) __syncthreads();
    }

    if (EPI == 0) {
        _Float16* C = (_Float16*)Cout;
#pragma unroll
        for (int i = 0; i < 4; i++) {
            int mbase = row0 + wm + i * 16 + quad * 4;
#pragma unroll
            for (int j = 0; j < 4; j++) {
                int n = col0 + wn + j * 16 + fr;
#pragma unroll
                for (int r = 0; r < 4; r++) {
                    int m = mbase + r;
                    if (m < M) C[(size_t)m * Nn + n] = (_Float16)acc[i][j][r];
                }
            }
        }
    } else {
        float* C = (float*)Cout;
        float bv[4];
#pragma unroll
        for (int j = 0; j < 4; j++) bv[j] = bias[col0 + wn + j * 16 + fr];
#pragma unroll
        for (int i = 0; i < 4; i++) {
            int mbase = row0 + wm + i * 16 + quad * 4;
#pragma unroll
            for (int j = 0; j < 4; j++) {
                int n = col0 + wn + j * 16 + fr;
#pragma unroll
                for (int r = 0; r < 4; r++) {
                    int m = mbase + r;
                    if (m < M) C[(size_t)m * Nn + n] = fmaxf(acc[i][j][r] + bv[j], 0.f);
                }
            }
        }
    }
}

// ---------------------------------------------------------------------------
// per-node attention coefficients from fp16 H
// ---------------------------------------------------------------------------
__global__ __launch_bounds__(256) void attn_kernel(
    const _Float16* __restrict__ H, const float* __restrict__ a_src,
    const float* __restrict__ a_dst, float* __restrict__ as_out,
    float* __restrict__ ad_out)
{
    int n = blockIdx.x;
    int t = threadIdx.x;
    int h = t >> 5, l = t & 31;
    f16x8 hv = *(const f16x8*)&H[(size_t)n * HC + h * HID + l * 8];
    const float* asp = a_src + h * HID + l * 8;
    const float* adp = a_dst + h * HID + l * 8;
    float sa = 0.f, sd = 0.f;
#pragma unroll
    for (int q = 0; q < 8; q++) {
        float v = (float)hv[q];
        sa = fmaf(v, asp[q], sa);
        sd = fmaf(v, adp[q], sd);
    }
#pragma unroll
    for (int o = 16; o > 0; o >>= 1) {
        sa += __shfl_xor(sa, o, 32);
        sd += __shfl_xor(sd, o, 32);
    }
    if (l == 0) { as_out[n * HEADS + h] = sa; ad_out[n * HEADS + h] = sd; }
}

// ---------------------------------------------------------------------------
// per-dst-node gather aggregation with segment softmax.  H is fp16.
// Round-4: SINGLE-PASS softmax fast path for deg <= 64 (covers all nodes
// w.h.p. for this random graph, avg deg 9): as_ is gathered ONCE into LDS
// (transposed al2[8][64]), max/exp/sum/scale run in-LDS (no memory latency),
// alpha read as float4 in the gather (4 edges per ds_read_b128).  This cuts
// the per-block serial latency chain from 4 random-gather stages to 2.
// General chunked path kept for deg > 64.  FP op order per element matches
// the round-3 kernel exactly (leaky -> exp(v-mx) -> /(sm+1e-16)).
// MODE 0: elu(sum + b1) -> fp16 [MPAD, HC]
// MODE 1: (mean over heads + b2) -> fp16 [MPAD, HID]
// ---------------------------------------------------------------------------
template <int MODE>
__global__ __launch_bounds__(256) void agg_kernel(
    const _Float16* __restrict__ H, const float* __restrict__ as_,
    const float* __restrict__ ad_, const float* __restrict__ bias,
    const int* __restrict__ indptr, const int* __restrict__ sorted,
    const int* __restrict__ ei, _Float16* __restrict__ outh)
{
    __shared__ float m8[HEADS], d8[HEADS], adl[HEADS];
    __shared__ int   srcl[64];
    __shared__ float al2[HEADS][64];   // alpha, transposed: [head][edge]
    __shared__ float red[HC];          // MODE 1 cross-head reduction

    int n = blockIdx.x;
    int t = threadIdx.x;

    if (n >= NNODES) {                 // pad rows for the next MFMA GEMM
        if (MODE == 0) {
            _Float16 z8[8] = {};
            *(f16x8*)&outh[(size_t)n * HC + t * 8] = *(f16x8*)z8;
        } else {
            outh[(size_t)n * HID + t] = (_Float16)0.f;
        }
        return;
    }

    int start = indptr[n];
    int deg = indptr[n + 1] - start;

    if (t < HEADS) adl[t] = ad_[n * HEADS + t];
    __syncthreads();

    int hh = t >> 5, c8 = (t & 31) * 8;
    const size_t hoff = (size_t)hh * HID + c8;
    float acc[8] = {};

    if (deg <= 64) {
        // ---- fast path: one chunk, single gather of as_, in-LDS softmax ----
        if (t < deg) srcl[t] = edge_src(ei, sorted[start + t]);
        __syncthreads();
        {
            int j = t & 63, h0 = t >> 6;          // h0 in 0..3
            if (j < deg) {
                int s = srcl[j];
#pragma unroll
                for (int q = 0; q < 2; q++) {
                    int hx = h0 + q * 4;
                    float v = as_[s * HEADS + hx] + adl[hx];
                    v = (v >= 0.f) ? v : NEG_SLOPE * v;
                    al2[hx][j] = v;
                }
            }
        }
        __syncthreads();
        {
            int h = t >> 5, l = t & 31;
            float mx = -1e30f;
            for (int jj = l; jj < deg; jj += 32) mx = fmaxf(mx, al2[h][jj]);
#pragma unroll
            for (int o = 16; o > 0; o >>= 1) mx = fmaxf(mx, __shfl_xor(mx, o, 32));
            float sm = 0.f;
            for (int jj = l; jj < deg; jj += 32) {
                float e = expf(al2[h][jj] - mx);
                al2[h][jj] = e;
                sm += e;
            }
#pragma unroll
            for (int o = 16; o > 0; o >>= 1) sm += __shfl_xor(sm, o, 32);
            float den = sm + 1e-16f;
            for (int jj = l; jj < deg; jj += 32) al2[h][jj] = al2[h][jj] / den;
        }
        __syncthreads();
        // ---- gather: 4 edges per step, alpha via one float4 LDS read ----
        int jj = 0;
        for (; jj + 3 < deg; jj += 4) {
            int sx0 = srcl[jj + 0], sx1 = srcl[jj + 1];
            int sx2 = srcl[jj + 2], sx3 = srcl[jj + 3];
            f16x8 h0v = *(const f16x8*)&H[(size_t)sx0 * HC + hoff];
            f16x8 h1v = *(const f16x8*)&H[(size_t)sx1 * HC + hoff];
            f16x8 h2v = *(const f16x8*)&H[(size_t)sx2 * HC + hoff];
            f16x8 h3v = *(const f16x8*)&H[(size_t)sx3 * HC + hoff];
            float4 a4 = *(const float4*)&al2[hh][jj];
#pragma unroll
            for (int q = 0; q < 8; q++) acc[q] = fmaf(a4.x, (float)h0v[q], acc[q]);
#pragma unroll
            for (int q = 0; q < 8; q++) acc[q] = fmaf(a4.y, (float)h1v[q], acc[q]);
#pragma unroll
            for (int q = 0; q < 8; q++) acc[q] = fmaf(a4.z, (float)h2v[q], acc[q]);
#pragma unroll
            for (int q = 0; q < 8; q++) acc[q] = fmaf(a4.w, (float)h3v[q], acc[q]);
        }
        for (; jj < deg; jj++) {
            int s = srcl[jj];
            f16x8 hv = *(const f16x8*)&H[(size_t)s * HC + hoff];
            float a = al2[hh][jj];
#pragma unroll
            for (int q = 0; q < 8; q++)
                acc[q] = fmaf(a, (float)hv[q], acc[q]);
        }
    } else {
        // ---- general chunked path (deg > 64, rare) — round-3 structure ----
        int h = t >> 5, l = t & 31;
        float adh = adl[h];

        float mx = -1e30f;
        for (int j = l; j < deg; j += 32) {
            int e = sorted[start + j];
            int s = edge_src(ei, e);
            float v = as_[s * HEADS + h] + adh;
            v = (v >= 0.f) ? v : NEG_SLOPE * v;
            mx = fmaxf(mx, v);
        }
#pragma unroll
        for (int o = 16; o > 0; o >>= 1) mx = fmaxf(mx, __shfl_xor(mx, o, 32));

        float sm = 0.f;
        for (int j = l; j < deg; j += 32) {
            int e = sorted[start + j];
            int s = edge_src(ei, e);
            float v = as_[s * HEADS + h] + adh;
            v = (v >= 0.f) ? v : NEG_SLOPE * v;
            sm += expf(v - mx);
        }
#pragma unroll
        for (int o = 16; o > 0; o >>= 1) sm += __shfl_xor(sm, o, 32);
        if (l == 0) { m8[h] = mx; d8[h] = sm; }

        for (int base = 0; base < deg; base += 64) {
            int cntc = min(64, deg - base);
            __syncthreads();
            if (t < cntc) srcl[t] = edge_src(ei, sorted[start + base + t]);
            __syncthreads();
            {
                int j = t & 63, h0 = t >> 6;
                if (j < cntc) {
                    int s = srcl[j];
#pragma unroll
                    for (int q = 0; q < 2; q++) {
                        int hx = h0 + q * 4;
                        float v = as_[s * HEADS + hx] + adl[hx];
                        v = (v >= 0.f) ? v : NEG_SLOPE * v;
                        al2[hx][j] = expf(v - m8[hx]) / (d8[hx] + 1e-16f);
                    }
                }
            }
            __syncthreads();
            int jj = 0;
            for (; jj + 3 < cntc; jj += 4) {
                int sx0 = srcl[jj + 0], sx1 = srcl[jj + 1];
                int sx2 = srcl[jj + 2], sx3 = srcl[jj + 3];
                f16x8 h0v = *(const f16x8*)&H[(size_t)sx0 * HC + hoff];
                f16x8 h1v = *(const f16x8*)&H[(size_t)sx1 * HC + hoff];
                f16x8 h2v = *(const f16x8*)&H[(size_t)sx2 * HC + hoff];
                f16x8 h3v = *(const f16x8*)&H[(size_t)sx3 * HC + hoff];
                float4 a4 = *(const float4*)&al2[hh][jj];
#pragma unroll
                for (int q = 0; q < 8; q++) acc[q] = fmaf(a4.x, (float)h0v[q], acc[q]);
#pragma unroll
                for (int q = 0; q < 8; q++) acc[q] = fmaf(a4.y, (float)h1v[q], acc[q]);
#pragma unroll
                for (int q = 0; q < 8; q++) acc[q] = fmaf(a4.z, (float)h2v[q], acc[q]);
#pragma unroll
                for (int q = 0; q < 8; q++) acc[q] = fmaf(a4.w, (float)h3v[q], acc[q]);
            }
            for (; jj < cntc; jj++) {
                int s = srcl[jj];
                f16x8 hv = *(const f16x8*)&H[(size_t)s * HC + hoff];
                float a = al2[hh][jj];
#pragma unroll
                for (int q = 0; q < 8; q++)
                    acc[q] = fmaf(a, (float)hv[q], acc[q]);
            }
        }
    }

    if (MODE == 0) {
        _Float16 o8[8];
#pragma unroll
        for (int q = 0; q < 8; q++) {
            float v = acc[q] + bias[hoff + q];
            v = (v > 0.f) ? v : expm1f(v);          // ELU (alpha=1)
            o8[q] = (_Float16)v;
        }
        *(f16x8*)&outh[(size_t)n * HC + hoff] = *(f16x8*)o8;
    } else {
#pragma unroll
        for (int q = 0; q < 8; q++) red[hoff + q] = acc[q];
        __syncthreads();
        float s = 0.f;
#pragma unroll
        for (int h2 = 0; h2 < HEADS; h2++) s += red[h2 * HID + t];
        outh[(size_t)n * HID + t] = (_Float16)(s * 0.125f + bias[t]);
    }
}

// ---------------------------------------------------------------------------
extern "C" void kernel_launch(void* const* d_in, const int* in_sizes, int n_in,
                              void* d_out, int out_size, void* d_ws, size_t ws_size,
                              hipStream_t stream)
{
    const float* x      = (const float*)d_in[0];
    const int*   ei     = (const int*)  d_in[1];
    const float* W1     = (const float*)d_in[2];
    const float* a_src1 = (const float*)d_in[3];
    const float* a_dst1 = (const float*)d_in[4];
    const float* b1     = (const float*)d_in[5];
    const float* W2     = (const float*)d_in[6];
    const float* a_src2 = (const float*)d_in[7];
    const float* a_dst2 = (const float*)d_in[8];
    const float* b2     = (const float*)d_in[9];
    const float* Wp     = (const float*)d_in[10];
    const float* bp     = (const float*)d_in[11];
    float* out = (float*)d_out;

    char* ws = (char*)d_ws;
    size_t off = 0;
    auto alloc = [&](size_t bytes) -> char* {
        char* p = ws + off;
        off += (bytes + 255) & ~(size_t)255;
        return p;
    };
    _Float16* Hbuf = (_Float16*)alloc((size_t)NNODES * HC * 2);          // 41 MB (H1, then H2)
    _Float16* A2   = (_Float16*)alloc((size_t)MPAD * HC * 2);            // 41.9 MB
    _Float16* W1t  = (_Float16*)alloc((size_t)HC * IN_DIM * 2);          // 3.1 MB
    _Float16* W2t  = (_Float16*)alloc((size_t)HC * HC * 2);              // 8.4 MB
    _Float16* Wpt  = (_Float16*)alloc((size_t)HID * HID * 2);            // 128 KB
    _Float16* xh   = (_Float16*)alloc((size_t)MPAD * IN_DIM * 2);        // 15.7 MB
    _Float16* out2h = (_Float16*)alloc((size_t)MPAD * HID * 2);          // 5.2 MB
    float* asad   = (float*)alloc((size_t)4 * NNODES * HEADS * sizeof(float));
    float* as1 = asad;
    float* ad1 = asad + (size_t)NNODES * HEADS;
    float* as2 = asad + (size_t)2 * NNODES * HEADS;
    float* ad2 = asad + (size_t)3 * NNODES * HEADS;
    int*   cntcur = (int*)alloc((size_t)2 * NNODES * sizeof(int));   // cnt | cur contiguous
    int*   cnt = cntcur;
    int*   cur = cntcur + NNODES;
    int*   indptr = (int*)  alloc((size_t)(NNODES + 1) * sizeof(int));
    int*   sorted = (int*)  alloc((size_t)E_TOT * sizeof(int));

    // --- one memset for cnt+cur, then fused prep (cvt + count + 3 transposes)
    hipMemsetAsync(cntcur, 0, (size_t)2 * NNODES * sizeof(int), stream);
    prep_kernel<<<PREP_BLK, 256, 0, stream>>>(x, xh, ei, cnt,
                                              W1, W1t, W2, W2t, Wp, Wpt);
    scan_kernel<<<1, 1024, 0, stream>>>(cnt, indptr);
    scatter_kernel<<<(E_TOT + 255) / 256, 256, 0, stream>>>(ei, indptr, cur, sorted);

    dim3 g8(HC / 256, MPAD / 320);   // 8 x 32 = 256 blocks = one full round

    // Layer 1: H1 = x @ W1 (8-phase 320x256 fp16 MFMA)
    gemm8p_kernel<<<g8, 512, 0, stream>>>(xh, W1t, Hbuf, NNODES, IN_DIM, HC);
    attn_kernel<<<NNODES, 256, 0, stream>>>(Hbuf, a_src1, a_dst1, as1, ad1);
    agg_kernel<0><<<MPAD, 256, 0, stream>>>(Hbuf, as1, ad1, b1, indptr, sorted, ei, A2);

    // Layer 2: H2 = elu_agg @ W2 (8-phase 320x256 fp16 MFMA)
    gemm8p_kernel<<<g8, 512, 0, stream>>>(A2, W2t, Hbuf, NNODES, HC, HC);
    attn_kernel<<<NNODES, 256, 0, stream>>>(Hbuf, a_src2, a_dst2, as2, ad2);
    agg_kernel<1><<<MPAD, 256, 0, stream>>>(Hbuf, as2, ad2, b2, indptr, sorted, ei, out2h);

    // Projection + ReLU (128^2 fp16 MFMA, bias+relu fp32 epilogue)
    dim3 gProj(HID / 128, MPAD / 128);   // 2 x 80
    mfma_gemm_kernel<1><<<gProj, 256, 0, stream>>>(out2h, Wpt, out, bp,
                                                   NNODES, HID, HID, 0);
}